// Round 7
// baseline (1357.533 us; speedup 1.0000x reference)
//
#include <hip/hip_runtime.h>
#include <hip/hip_bf16.h>

#define NN 528
#define NP (NN*NN)
#define IMG 512
#define IMGP (IMG*IMG)
#define PAD 8
#define KH 17
#define KT (KH*KH)
#define NF 24
#define RK 5
#define RKT (RK*RK)
#define ND 4

static __device__ __forceinline__ float ldx(const void* p, long i, int bf) {
    if (bf) return __bfloat162float(((const __hip_bfloat16*)p)[i]);
    return ((const float*)p)[i];
}

// K(kr=u, kc=v) = sum_{j,k} psf[j][k] e^{-2pi i (u(j-8)+v(k-8))/528}
static __device__ float2 dev_K(int u, int v, const float* __restrict__ psf,
                               const float2* __restrict__ twN) {
    float Kr = 0.f, Ki = 0.f;
    for (int j = 0; j < KH; ++j) {
        int m = (u * (j - PAD)) % NN; if (m < 0) m += NN;
        float2 rp = twN[m];
        float sr = 0.f, si = 0.f;
        for (int k = 0; k < KH; ++k) {
            int m2 = (v * (k - PAD)) % NN; if (m2 < 0) m2 += NN;
            float2 cp = twN[m2];
            float pv = psf[j*KH + k];
            sr += pv * cp.x;
            si += pv * cp.y;
        }
        Kr += rp.x*sr - rp.y*si;
        Ki += rp.x*si + rp.y*sr;
    }
    return make_float2(Kr, Ki);
}

static __device__ __forceinline__ float fetch_pad(const void* img, long ofs, int bf,
                                                  int rr, int cc) {
    int sr = rr - PAD; sr = sr < 0 ? -sr-1 : (sr >= IMG ? 2*IMG-1-sr : sr);
    int sc = cc - PAD; sc = sc < 0 ? -sc-1 : (sc >= IMG ? 2*IMG-1-sc : sc);
    return ldx(img, ofs + sr*IMG + sc, bf);
}

// flags[0..3]: dtype of image/blurKernel/wcw/wscale. Also routes the two
// size-4 tensors into alpha_ws / wgt_ws by sign (alpha = ln(1e-3..1e-1) < 0).
__global__ void detect_k(const void* pimg, int nimg, const void* pbk, int nbk,
                         const void* pwcw, int nwcw, const void* pws, int nws,
                         const float* c4a, const float* c4b,
                         int* __restrict__ flags,
                         float* __restrict__ alpha_ws, float* __restrict__ wgt_ws) {
    int t = threadIdx.x;
    const void* ps[4] = {pimg, pbk, pwcw, pws};
    int ns[4] = {nimg, nbk, nwcw, nws};
    if (t < 4) {
        const unsigned short* q = (const unsigned short*)ps[t];
        int n = ns[t];
        int K = n < 512 ? n : 512;
        int cnt = 0, pass = 0;
        for (int i = 0; i < K; i += 2) {
            int e = (q[i] >> 7) & 0xFF;
            pass += (e >= 100 && e <= 140);
            cnt++;
        }
        flags[t] = (pass * 10 >= cnt * 8) ? 1 : 0;
    }
    if (t == 7) {
        const float* A = (c4a[0] < 0.f) ? c4a : c4b;
        const float* W = (c4a[0] < 0.f) ? c4b : c4a;
        for (int i = 0; i < ND; ++i) { alpha_ws[i] = A[i]; wgt_ws[i] = W[i]; }
    }
}

__global__ void twinit_k(float2* __restrict__ twN) {
    int i = blockIdx.x * blockDim.x + threadIdx.x;
    if (i < NN) {
        double th = -6.283185307179586476925287 * (double)i / (double)NN;
        twN[i] = make_float2((float)cos(th), (float)sin(th));
    }
}

__global__ void wnorm_k(const void* __restrict__ wcw, const void* __restrict__ wscale,
                        const int* __restrict__ flags, float* __restrict__ wout) {
    int f = threadIdx.x;
    if (f >= NF) return;
    int bfw = flags[2], bfs = flags[3];
    float v[RKT];
    float mean = 0.f;
    for (int i = 0; i < RKT; ++i) { v[i] = ldx(wcw, f*RKT+i, bfw); mean += v[i]; }
    mean *= (1.f/(float)RKT);
    float ss = 0.f;
    for (int i = 0; i < RKT; ++i) { v[i] -= mean; ss += v[i]*v[i]; }
    float sc = ldx(wscale, f, bfs) / sqrtf(ss);
    for (int i = 0; i < RKT; ++i) wout[f*RKT+i] = v[i]*sc;
}

__global__ void prep_k(const void* __restrict__ blurKernel, const int* __restrict__ flags,
                       float* __restrict__ psf_all, float* __restrict__ A0_all,
                       float* __restrict__ A1_all) {
    int b = blockIdx.x, t = threadIdx.x;
    int bf = flags[1];
    __shared__ float psf[KT];
    __shared__ float q0[KH], q1[KH], ac0[KH], ac1[KH];
    for (int i = t; i < KT; i += 64) {
        float v = ldx(blurKernel, b*KT + i, bf);
        psf[i] = v;
        psf_all[b*KT + i] = v;
    }
    __syncthreads();
    if (t < KH) {
        float s0 = 0.f, s1 = 0.f;
        for (int k = 0; k < KH; ++k) { s0 += psf[t*KH + k]; s1 += psf[k*KH + t]; }
        q0[t] = s0; q1[t] = s1;
    }
    __syncthreads();
    if (t < KH) {
        float a0 = 0.f, a1 = 0.f;
        for (int m = 0; m + t < KH; ++m) { a0 += q0[m]*q0[m+t]; a1 += q1[m]*q1[m+t]; }
        ac0[t] = a0; ac1[t] = a1;
    }
    __syncthreads();
    for (int r = t; r < NN; r += 64) {
        int lag = min(r, (NN-1) - r);   // circular autocorr len 527 + appended z[0]
        float b0 = (lag <= KH-1) ? ac0[lag]/ac0[0] : 0.f;
        float b1 = (lag <= KH-1) ? ac1[lag]/ac1[0] : 0.f;
        A0_all[b*NN + r] = 1.f - b0;
        A1_all[b*NN + r] = 1.f - b1;
    }
}

// Greg in transposed frequency layout: p = kc*NN + kr  (verified vs literal FFT path, R6)
__global__ void greg_k(const float* __restrict__ w, const float2* __restrict__ twN,
                       float* __restrict__ Greg) {
    int p = blockIdx.x * blockDim.x + threadIdx.x;
    if (p >= NP) return;
    int u = p % NN, v = p / NN;
    float2 rp[RK], cp[RK];
    for (int j = 0; j < RK; ++j) {
        int m = (u * (j - RK/2)) % NN; if (m < 0) m += NN;
        rp[j] = twN[m];
    }
    for (int k = 0; k < RK; ++k) {
        int m = (v * (k - RK/2)) % NN; if (m < 0) m += NN;
        cp[k] = twN[m];
    }
    float pr[RKT], pi[RKT];
    for (int j = 0; j < RK; ++j)
        for (int k = 0; k < RK; ++k) {
            pr[j*RK+k] = rp[j].x*cp[k].x - rp[j].y*cp[k].y;
            pi[j*RK+k] = rp[j].x*cp[k].y + rp[j].y*cp[k].x;
        }
    float acc = 0.f;
    for (int f = 0; f < NF; ++f) {
        float gr = 0.f, gi = 0.f;
        for (int i = 0; i < RKT; ++i) {
            float wv = w[f*RKT + i];
            gr += wv * pr[i];
            gi += wv * pi[i];
        }
        acc += gr*gr + gi*gi;
    }
    Greg[p] = acc;
}

// combined filter: conj(K) * sum_d w_d/S_d * (1/N^2)   (verified vs per-d literal path, R6)
__global__ void wfilt_k(const float* __restrict__ psf, const float* __restrict__ Greg,
                        const float2* __restrict__ twN, const float* __restrict__ alpha4,
                        const float* __restrict__ wgt4, float2* __restrict__ Wfilt) {
    int p = blockIdx.x * blockDim.x + threadIdx.x;
    if (p >= NP) return;
    int u = p % NN, v = p / NN;
    float2 K = dev_K(u, v, psf, twN);
    float K2 = K.x*K.x + K.y*K.y;
    float g = Greg[p];
    float ssum = 0.f;
    for (int d = 0; d < ND; ++d) {
        float a  = __expf(alpha4[d]);
        ssum += wgt4[d] / fmaxf(K2 + a*g, 1e-30f);
    }
    ssum *= (1.f/(float)NP);
    Wfilt[p] = make_float2(K.x*ssum, -K.y*ssum);
}

__global__ void edgetaper_k(const void* __restrict__ image, const int* __restrict__ flags,
                            const float* __restrict__ psf, const float* __restrict__ A0,
                            const float* __restrict__ A1, float2* __restrict__ outbuf, int b) {
    int idx = blockIdx.x * blockDim.x + threadIdx.x;
    if (idx >= 3*NP) return;
    int bf = flags[0];
    int ch = idx / NP, p = idx % NP;
    int r = p / NN, c = p % NN;
    long ofs = ((long)b*3 + ch) * IMGP;
    float a0 = A0[r], a1 = A1[c];
    float xv = fetch_pad(image, ofs, bf, r, c);
    float res;
    if (a0 == 1.f && a1 == 1.f) {
        res = xv;   // alpha==1 exactly in the interior -> blend is identity
    } else {
        float alpha = a0 * a1;
        float blur = 0.f;
        for (int j = 0; j < KH; ++j) {
            int rr = r - (j - PAD); rr = (rr + NN) % NN;
            for (int k = 0; k < KH; ++k) {
                int cc = c - (k - PAD); cc = (cc + NN) % NN;
                blur += psf[j*KH + k] * fetch_pad(image, ofs, bf, rr, cc);
            }
        }
        res = alpha*xv + (1.f - alpha)*blur;
    }
    outbuf[(size_t)ch*NP + p] = make_float2(res, 0.f);
}

// 1D FFT (528 = 16*33), one block per row  (verified vs naive DFT on HW, R4)
__global__ __launch_bounds__(128)
void fft_pass(const float2* __restrict__ in, float2* __restrict__ out,
              const float2* __restrict__ twN, int inv) {
    __shared__ float2 X[NN];
    __shared__ float2 A[NN];
    __shared__ float2 TW[NN];
    int t = threadIdx.x;
    const float2* src = in + (size_t)blockIdx.x * NN;
    float2* dst = out + (size_t)blockIdx.x * NN;
    for (int i = t; i < NN; i += 128) { X[i] = src[i]; TW[i] = twN[i]; }
    __syncthreads();
    float s = inv ? -1.f : 1.f;
    for (int o = t; o < NN; o += 128) {
        int n1 = o & 15, k2 = o >> 4;
        float ar = 0.f, ai = 0.f;
        int m = 0;
        for (int n2 = 0; n2 < 33; ++n2) {
            float2 xv = X[n1 + 16*n2];
            float2 w = TW[m * 16];
            float wr = w.x, wi = w.y * s;
            ar += xv.x*wr - xv.y*wi;
            ai += xv.x*wi + xv.y*wr;
            m += k2; if (m >= 33) m -= 33;
        }
        float2 tw = TW[n1 * k2];
        float twr = tw.x, twi = tw.y * s;
        A[n1*33 + k2] = make_float2(ar*twr - ai*twi, ar*twi + ai*twr);
    }
    __syncthreads();
    for (int o = t; o < NN; o += 128) {
        int k1 = o / 33, k2 = o - 33*k1;
        float ar = 0.f, ai = 0.f;
        int m = 0;
        for (int n1 = 0; n1 < 16; ++n1) {
            float2 bv = A[n1*33 + k2];
            float2 w = TW[m * 33];
            float wr = w.x, wi = w.y * s;
            ar += bv.x*wr - bv.y*wi;
            ai += bv.x*wi + bv.y*wr;
            m = (m + k1) & 15;
        }
        dst[o] = make_float2(ar, ai);
    }
}

__global__ void transpose_k(const float2* __restrict__ in, float2* __restrict__ out) {
    __shared__ float2 tile[16][17];
    int ch = blockIdx.z;
    int c0 = blockIdx.x * 16, r0 = blockIdx.y * 16;
    const float2* src = in + (size_t)ch * NP;
    float2* dst = out + (size_t)ch * NP;
    int x = c0 + threadIdx.x, y = r0 + threadIdx.y;
    tile[threadIdx.y][threadIdx.x] = src[(size_t)y*NN + x];
    __syncthreads();
    int xo = r0 + threadIdx.x, yo = c0 + threadIdx.y;
    dst[(size_t)yo*NN + xo] = tile[threadIdx.x][threadIdx.y];
}

__global__ void cmul_k(float2* __restrict__ buf, const float2* __restrict__ wf) {
    int i = blockIdx.x * blockDim.x + threadIdx.x;
    if (i >= 3*NP) return;
    int p = i % NP;
    float2 a = buf[i], b = wf[p];
    buf[i] = make_float2(a.x*b.x - a.y*b.y, a.x*b.y + a.y*b.x);
}

// crop + store FP32  <-- the fix: d_out is float, not bf16
__global__ void crop_k(const float2* __restrict__ buf, float* __restrict__ out, int b) {
    int idx = blockIdx.x * blockDim.x + threadIdx.x;
    if (idx >= 3*IMGP) return;
    int ch = idx / IMGP, p = idx % IMGP;
    int r = p / IMG, c = p % IMG;
    float v = buf[(size_t)ch*NP + (size_t)(r+PAD)*NN + (c+PAD)].x;
    out[((size_t)b*3 + ch) * IMGP + p] = v;
}

extern "C" void kernel_launch(void* const* d_in, const int* in_sizes, int n_in,
                              void* d_out, int out_size, void* d_ws, size_t ws_size,
                              hipStream_t stream) {
    // size-based input remap (order-robust; sizes unique except the two 4-elem tensors)
    int i_img = -1, i_bk = -1, i_wcw = -1, i_ws = -1, i_4a = -1, i_4b = -1;
    for (int i = 0; i < n_in; ++i) {
        int s = in_sizes[i];
        if (s == 8*3*IMG*IMG)   i_img = i;
        else if (s == 8*KT)     i_bk = i;
        else if (s == NF*RKT)   i_wcw = i;
        else if (s == NF)       i_ws = i;
        else if (s == ND) { if (i_4a < 0) i_4a = i; else i_4b = i; }
    }
    if (i_img < 0) i_img = 0;
    if (i_bk  < 0) i_bk  = 1;
    if (i_wcw < 0) i_wcw = 3;
    if (i_ws  < 0) i_ws  = 4;
    if (i_4a  < 0) i_4a  = 5;
    if (i_4b  < 0) i_4b  = i_4a;
    const void* image      = d_in[i_img];
    const void* blurKernel = d_in[i_bk];
    const void* wcw        = d_in[i_wcw];
    const void* wscale     = d_in[i_ws];
    const float* c4a       = (const float*)d_in[i_4a];
    const float* c4b       = (const float*)d_in[i_4b];
    float* out = (float*)d_out;

    char* base = (char*)d_ws;
    int*    flags    = (int*)(base);
    float*  alpha_ws = (float*)(base + 64);
    float*  wgt_ws   = (float*)(base + 80);
    float2* twN      = (float2*)(base + 256);
    float*  wnorm    = (float*)(base + 4480);
    float*  psf_all  = (float*)(base + 6880);
    float*  A0       = (float*)(base + 16128);
    float*  A1       = (float*)(base + 33024);
    float*  Greg     = (float*)(base + 49920);      // NP f
    float2* Wfilt    = (float2*)(base + 1165056);   // NP f2
    float2* bufA     = (float2*)(base + 3395328);   // 3*NP f2
    float2* bufB     = (float2*)(base + 10086144);  // 3*NP f2, end 16776960

    if (ws_size < 16776960) return;

    detect_k<<<1, 64, 0, stream>>>(image, in_sizes[i_img], blurKernel, in_sizes[i_bk],
                                   wcw, in_sizes[i_wcw], wscale, in_sizes[i_ws],
                                   c4a, c4b, flags, alpha_ws, wgt_ws);
    twinit_k<<<(NN+63)/64, 64, 0, stream>>>(twN);
    wnorm_k<<<1, 64, 0, stream>>>(wcw, wscale, flags, wnorm);
    prep_k<<<8, 64, 0, stream>>>(blurKernel, flags, psf_all, A0, A1);
    greg_k<<<(NP+255)/256, 256, 0, stream>>>(wnorm, twN, Greg);

    dim3 tgrid(NN/16, NN/16, 3), tblk(16, 16);
    int nb = (NP+255)/256;

    for (int b = 0; b < 8; ++b) {
        edgetaper_k<<<(3*NP+255)/256, 256, 0, stream>>>(image, flags, psf_all + b*KT,
                                                        A0 + b*NN, A1 + b*NN, bufA, b);
        fft_pass<<<3*NN, 128, 0, stream>>>(bufA, bufB, twN, 0);     // rows fwd
        transpose_k<<<tgrid, tblk, 0, stream>>>(bufB, bufA);
        fft_pass<<<3*NN, 128, 0, stream>>>(bufA, bufB, twN, 0);     // cols fwd
        wfilt_k<<<nb, 256, 0, stream>>>(psf_all + b*KT, Greg, twN, alpha_ws, wgt_ws, Wfilt);
        cmul_k<<<(3*NP+255)/256, 256, 0, stream>>>(bufB, Wfilt);
        fft_pass<<<3*NN, 128, 0, stream>>>(bufB, bufA, twN, 1);     // cols inv
        transpose_k<<<tgrid, tblk, 0, stream>>>(bufA, bufB);
        fft_pass<<<3*NN, 128, 0, stream>>>(bufB, bufA, twN, 1);     // rows inv
        crop_k<<<(3*IMGP+255)/256, 256, 0, stream>>>(bufA, out, b);
    }
}

// Round 8
// 1162.966 us; speedup vs baseline: 1.1673x; 1.1673x over previous
//
#include <hip/hip_runtime.h>
#include <hip/hip_bf16.h>

#define NN 528
#define NP (NN*NN)
#define IMG 512
#define IMGP (IMG*IMG)
#define PAD 8
#define KH 17
#define KT (KH*KH)
#define NF 24
#define RK 5
#define RKT (RK*RK)
#define ND 4

static __device__ __forceinline__ float ldx(const void* p, long i, int bf) {
    if (bf) return __bfloat162float(((const __hip_bfloat16*)p)[i]);
    return ((const float*)p)[i];
}

static __device__ __forceinline__ float fetch_pad(const void* img, long ofs, int bf,
                                                  int rr, int cc) {
    int sr = rr - PAD; sr = sr < 0 ? -sr-1 : (sr >= IMG ? 2*IMG-1-sr : sr);
    int sc = cc - PAD; sc = sc < 0 ? -sc-1 : (sc >= IMG ? 2*IMG-1-sc : sc);
    return ldx(img, ofs + sr*IMG + sc, bf);
}

// flags[0..3]: dtype of image/blurKernel/wcw/wscale; routes size-4 tensors by sign.
__global__ void detect_k(const void* pimg, int nimg, const void* pbk, int nbk,
                         const void* pwcw, int nwcw, const void* pws, int nws,
                         const float* c4a, const float* c4b,
                         int* __restrict__ flags,
                         float* __restrict__ alpha_ws, float* __restrict__ wgt_ws) {
    int t = threadIdx.x;
    const void* ps[4] = {pimg, pbk, pwcw, pws};
    int ns[4] = {nimg, nbk, nwcw, nws};
    if (t < 4) {
        const unsigned short* q = (const unsigned short*)ps[t];
        int n = ns[t];
        int K = n < 512 ? n : 512;
        int cnt = 0, pass = 0;
        for (int i = 0; i < K; i += 2) {
            int e = (q[i] >> 7) & 0xFF;
            pass += (e >= 100 && e <= 140);
            cnt++;
        }
        flags[t] = (pass * 10 >= cnt * 8) ? 1 : 0;
    }
    if (t == 7) {
        const float* A = (c4a[0] < 0.f) ? c4a : c4b;
        const float* W = (c4a[0] < 0.f) ? c4b : c4a;
        for (int i = 0; i < ND; ++i) { alpha_ws[i] = A[i]; wgt_ws[i] = W[i]; }
    }
}

__global__ void twinit_k(float2* __restrict__ twN) {
    int i = blockIdx.x * blockDim.x + threadIdx.x;
    if (i < NN) {
        double th = -6.283185307179586476925287 * (double)i / (double)NN;
        twN[i] = make_float2((float)cos(th), (float)sin(th));
    }
}

__global__ void wnorm_k(const void* __restrict__ wcw, const void* __restrict__ wscale,
                        const int* __restrict__ flags, float* __restrict__ wout) {
    int f = threadIdx.x;
    if (f >= NF) return;
    int bfw = flags[2], bfs = flags[3];
    float v[RKT];
    float mean = 0.f;
    for (int i = 0; i < RKT; ++i) { v[i] = ldx(wcw, f*RKT+i, bfw); mean += v[i]; }
    mean *= (1.f/(float)RKT);
    float ss = 0.f;
    for (int i = 0; i < RKT; ++i) { v[i] -= mean; ss += v[i]*v[i]; }
    float sc = ldx(wscale, f, bfs) / sqrtf(ss);
    for (int i = 0; i < RKT; ++i) wout[f*RKT+i] = v[i]*sc;
}

__global__ void prep_k(const void* __restrict__ blurKernel, const int* __restrict__ flags,
                       float* __restrict__ psf_all, float* __restrict__ A0_all,
                       float* __restrict__ A1_all) {
    int b = blockIdx.x, t = threadIdx.x;
    int bf = flags[1];
    __shared__ float psf[KT];
    __shared__ float q0[KH], q1[KH], ac0[KH], ac1[KH];
    for (int i = t; i < KT; i += 64) {
        float v = ldx(blurKernel, b*KT + i, bf);
        psf[i] = v;
        psf_all[b*KT + i] = v;
    }
    __syncthreads();
    if (t < KH) {
        float s0 = 0.f, s1 = 0.f;
        for (int k = 0; k < KH; ++k) { s0 += psf[t*KH + k]; s1 += psf[k*KH + t]; }
        q0[t] = s0; q1[t] = s1;
    }
    __syncthreads();
    if (t < KH) {
        float a0 = 0.f, a1 = 0.f;
        for (int m = 0; m + t < KH; ++m) { a0 += q0[m]*q0[m+t]; a1 += q1[m]*q1[m+t]; }
        ac0[t] = a0; ac1[t] = a1;
    }
    __syncthreads();
    for (int r = t; r < NN; r += 64) {
        int lag = min(r, (NN-1) - r);
        float b0 = (lag <= KH-1) ? ac0[lag]/ac0[0] : 0.f;
        float b1 = (lag <= KH-1) ? ac1[lag]/ac1[0] : 0.f;
        A0_all[b*NN + r] = 1.f - b0;
        A1_all[b*NN + r] = 1.f - b1;
    }
}

// Greg in transposed frequency layout: p = kc*NN + kr (verified R6)
__global__ void greg_k(const float* __restrict__ w, const float2* __restrict__ twN,
                       float* __restrict__ Greg) {
    int p = blockIdx.x * blockDim.x + threadIdx.x;
    if (p >= NP) return;
    int u = p % NN, v = p / NN;
    float2 rp[RK], cp[RK];
    for (int j = 0; j < RK; ++j) {
        int m = (u * (j - RK/2)) % NN; if (m < 0) m += NN;
        rp[j] = twN[m];
    }
    for (int k = 0; k < RK; ++k) {
        int m = (v * (k - RK/2)) % NN; if (m < 0) m += NN;
        cp[k] = twN[m];
    }
    float pr[RKT], pi[RKT];
    for (int j = 0; j < RK; ++j)
        for (int k = 0; k < RK; ++k) {
            pr[j*RK+k] = rp[j].x*cp[k].x - rp[j].y*cp[k].y;
            pi[j*RK+k] = rp[j].x*cp[k].y + rp[j].y*cp[k].x;
        }
    float acc = 0.f;
    for (int f = 0; f < NF; ++f) {
        float gr = 0.f, gi = 0.f;
        for (int i = 0; i < RKT; ++i) {
            float wv = w[f*RKT + i];
            gr += wv * pr[i];
            gi += wv * pi[i];
        }
        acc += gr*gr + gi*gi;
    }
    Greg[p] = acc;
}

// Wiener filters for BOTH batches of a pair, shared twiddle setup.
// W_b = conj(K_b) * sum_d w_d / (|K_b|^2 + a_d Greg) * (1/N^2)
__global__ __launch_bounds__(256)
void wfiltpair_k(const float* __restrict__ psf_all, int b0,
                 const float* __restrict__ Greg, const float2* __restrict__ twN,
                 const float* __restrict__ alpha4, const float* __restrict__ wgt4,
                 float2* __restrict__ Wfilt2) {
    __shared__ float sps[2*KT];
    for (int i = threadIdx.x; i < 2*KT; i += 256)
        sps[i] = psf_all[b0*KT + i];
    __syncthreads();
    int p = blockIdx.x * blockDim.x + threadIdx.x;
    if (p >= NP) return;
    int u = p % NN, v = p / NN;
    float2 rph[KH], cph[KH];
    int mu = (520 * u) % NN;   // (-8u) mod 528
    int mv = (520 * v) % NN;
    for (int j = 0; j < KH; ++j) {
        rph[j] = twN[mu]; mu += u; if (mu >= NN) mu -= NN;
        cph[j] = twN[mv]; mv += v; if (mv >= NN) mv -= NN;
    }
    float K0r = 0.f, K0i = 0.f, K1r = 0.f, K1i = 0.f;
    for (int j = 0; j < KH; ++j) {
        float sr0 = 0.f, si0 = 0.f, sr1 = 0.f, si1 = 0.f;
        for (int k = 0; k < KH; ++k) {
            float2 cp = cph[k];
            float p0 = sps[j*KH + k];
            float p1 = sps[KT + j*KH + k];
            sr0 += p0 * cp.x; si0 += p0 * cp.y;
            sr1 += p1 * cp.x; si1 += p1 * cp.y;
        }
        float2 rp = rph[j];
        K0r += rp.x*sr0 - rp.y*si0;  K0i += rp.x*si0 + rp.y*sr0;
        K1r += rp.x*sr1 - rp.y*si1;  K1i += rp.x*si1 + rp.y*sr1;
    }
    float g = Greg[p];
    float K20 = K0r*K0r + K0i*K0i;
    float K21 = K1r*K1r + K1i*K1i;
    float s0 = 0.f, s1 = 0.f;
    for (int d = 0; d < ND; ++d) {
        float a = __expf(alpha4[d]);
        float wd = wgt4[d];
        s0 += wd / fmaxf(K20 + a*g, 1e-30f);
        s1 += wd / fmaxf(K21 + a*g, 1e-30f);
    }
    s0 *= (1.f/(float)NP);
    s1 *= (1.f/(float)NP);
    Wfilt2[p]      = make_float2(K0r*s0, -K0i*s0);
    Wfilt2[NP + p] = make_float2(K1r*s1, -K1i*s1);
}

// pack two batches' edgetapered planes: out = et(b0) + i*et(b1)
__global__ void packet_k(const void* __restrict__ image, const int* __restrict__ flags,
                         const float* __restrict__ psf_all,
                         const float* __restrict__ A0_all, const float* __restrict__ A1_all,
                         float2* __restrict__ outbuf, int b0) {
    int idx = blockIdx.x * blockDim.x + threadIdx.x;
    if (idx >= 3*NP) return;
    int bf = flags[0];
    int ch = idx / NP, p = idx % NP;
    int r = p / NN, c = p % NN;
    long ofs0 = ((long)b0*3 + ch) * IMGP;
    long ofs1 = ofs0 + 3L*IMGP;
    const float* ps0 = psf_all + b0*KT;
    const float* ps1 = ps0 + KT;
    float a00 = A0_all[b0*NN + r], a10 = A1_all[b0*NN + c];
    float a01 = A0_all[(b0+1)*NN + r], a11 = A1_all[(b0+1)*NN + c];
    float x0 = fetch_pad(image, ofs0, bf, r, c);
    float x1 = fetch_pad(image, ofs1, bf, r, c);
    float res0, res1;
    bool i0 = (a00 == 1.f && a10 == 1.f);
    bool i1 = (a01 == 1.f && a11 == 1.f);
    if (i0 && i1) {
        res0 = x0; res1 = x1;
    } else {
        float bl0 = 0.f, bl1 = 0.f;
        for (int j = 0; j < KH; ++j) {
            int rr = r - (j - PAD); rr = (rr + NN) % NN;
            for (int k = 0; k < KH; ++k) {
                int cc = c - (k - PAD); cc = (cc + NN) % NN;
                float f0 = fetch_pad(image, ofs0, bf, rr, cc);
                float f1 = fetch_pad(image, ofs1, bf, rr, cc);
                bl0 += ps0[j*KH + k] * f0;
                bl1 += ps1[j*KH + k] * f1;
            }
        }
        float al0 = a00 * a10, al1 = a01 * a11;
        res0 = i0 ? x0 : al0*x0 + (1.f - al0)*bl0;
        res1 = i1 ? x1 : al1*x1 + (1.f - al1)*bl1;
    }
    outbuf[(size_t)ch*NP + p] = make_float2(res0, res1);
}

// 1D FFT (528 = 16*33), one block per row (HW-verified vs naive DFT, R4)
__global__ __launch_bounds__(128)
void fft_pass(const float2* __restrict__ in, float2* __restrict__ out,
              const float2* __restrict__ twN, int inv) {
    __shared__ float2 X[NN];
    __shared__ float2 A[NN];
    __shared__ float2 TW[NN];
    int t = threadIdx.x;
    const float2* src = in + (size_t)blockIdx.x * NN;
    float2* dst = out + (size_t)blockIdx.x * NN;
    for (int i = t; i < NN; i += 128) { X[i] = src[i]; TW[i] = twN[i]; }
    __syncthreads();
    float s = inv ? -1.f : 1.f;
    for (int o = t; o < NN; o += 128) {
        int n1 = o & 15, k2 = o >> 4;
        float ar = 0.f, ai = 0.f;
        int m = 0;
        for (int n2 = 0; n2 < 33; ++n2) {
            float2 xv = X[n1 + 16*n2];
            float2 w = TW[m * 16];
            float wr = w.x, wi = w.y * s;
            ar += xv.x*wr - xv.y*wi;
            ai += xv.x*wi + xv.y*wr;
            m += k2; if (m >= 33) m -= 33;
        }
        float2 tw = TW[n1 * k2];
        float twr = tw.x, twi = tw.y * s;
        A[n1*33 + k2] = make_float2(ar*twr - ai*twi, ar*twi + ai*twr);
    }
    __syncthreads();
    for (int o = t; o < NN; o += 128) {
        int k1 = o / 33, k2 = o - 33*k1;
        float ar = 0.f, ai = 0.f;
        int m = 0;
        for (int n1 = 0; n1 < 16; ++n1) {
            float2 bv = A[n1*33 + k2];
            float2 w = TW[m * 33];
            float wr = w.x, wi = w.y * s;
            ar += bv.x*wr - bv.y*wi;
            ai += bv.x*wi + bv.y*wr;
            m = (m + k1) & 15;
        }
        dst[o] = make_float2(ar, ai);
    }
}

__global__ void transpose_k(const float2* __restrict__ in, float2* __restrict__ out) {
    __shared__ float2 tile[16][17];
    int ch = blockIdx.z;
    int c0 = blockIdx.x * 16, r0 = blockIdx.y * 16;
    const float2* src = in + (size_t)ch * NP;
    float2* dst = out + (size_t)ch * NP;
    int x = c0 + threadIdx.x, y = r0 + threadIdx.y;
    tile[threadIdx.y][threadIdx.x] = src[(size_t)y*NN + x];
    __syncthreads();
    int xo = r0 + threadIdx.x, yo = c0 + threadIdx.y;
    dst[(size_t)yo*NN + xo] = tile[threadIdx.x][threadIdx.y];
}

// Hermitian unpack -> per-batch filter -> repack. Reads Z (in), writes out (separate buf).
__global__ void cmulpair_k(const float2* __restrict__ in, const float2* __restrict__ Wfilt2,
                           float2* __restrict__ out) {
    int i = blockIdx.x * blockDim.x + threadIdx.x;
    if (i >= 3*NP) return;
    int ch = i / NP, p = i % NP;
    int u = p % NN, v = p / NN;
    int um = (NN - u) % NN, vm = (NN - v) % NN;
    int pm = vm * NN + um;
    float2 Z  = in[(size_t)ch*NP + p];
    float2 Zm = in[(size_t)ch*NP + pm];
    // X0 = (Z + conj(Zm))/2 ; X1 = (Z - conj(Zm))/(2i)
    float X0r = 0.5f*(Z.x + Zm.x), X0i = 0.5f*(Z.y - Zm.y);
    float X1r = 0.5f*(Z.y + Zm.y), X1i = 0.5f*(Zm.x - Z.x);
    float2 W0 = Wfilt2[p], W1 = Wfilt2[NP + p];
    float Y0r = X0r*W0.x - X0i*W0.y, Y0i = X0r*W0.y + X0i*W0.x;
    float Y1r = X1r*W1.x - X1i*W1.y, Y1i = X1r*W1.y + X1i*W1.x;
    // repack Y = Y0 + i*Y1
    out[(size_t)ch*NP + p] = make_float2(Y0r - Y1i, Y0i + Y1r);
}

// crop: Re -> batch b0, Im -> batch b0+1
__global__ void croppair_k(const float2* __restrict__ buf, float* __restrict__ out, int b0) {
    int idx = blockIdx.x * blockDim.x + threadIdx.x;
    if (idx >= 3*IMGP) return;
    int ch = idx / IMGP, p = idx % IMGP;
    int r = p / IMG, c = p % IMG;
    float2 v = buf[(size_t)ch*NP + (size_t)(r+PAD)*NN + (c+PAD)];
    out[((size_t)b0*3 + ch) * IMGP + p] = v.x;
    out[((size_t)(b0+1)*3 + ch) * IMGP + p] = v.y;
}

extern "C" void kernel_launch(void* const* d_in, const int* in_sizes, int n_in,
                              void* d_out, int out_size, void* d_ws, size_t ws_size,
                              hipStream_t stream) {
    // size-based input remap (order-robust)
    int i_img = -1, i_bk = -1, i_wcw = -1, i_ws = -1, i_4a = -1, i_4b = -1;
    for (int i = 0; i < n_in; ++i) {
        int s = in_sizes[i];
        if (s == 8*3*IMG*IMG)   i_img = i;
        else if (s == 8*KT)     i_bk = i;
        else if (s == NF*RKT)   i_wcw = i;
        else if (s == NF)       i_ws = i;
        else if (s == ND) { if (i_4a < 0) i_4a = i; else i_4b = i; }
    }
    if (i_img < 0) i_img = 0;
    if (i_bk  < 0) i_bk  = 1;
    if (i_wcw < 0) i_wcw = 3;
    if (i_ws  < 0) i_ws  = 4;
    if (i_4a  < 0) i_4a  = 5;
    if (i_4b  < 0) i_4b  = i_4a;
    const void* image      = d_in[i_img];
    const void* blurKernel = d_in[i_bk];
    const void* wcw        = d_in[i_wcw];
    const void* wscale     = d_in[i_ws];
    const float* c4a       = (const float*)d_in[i_4a];
    const float* c4b       = (const float*)d_in[i_4b];
    float* out = (float*)d_out;

    char* base = (char*)d_ws;
    int*    flags    = (int*)(base);
    float*  alpha_ws = (float*)(base + 64);
    float*  wgt_ws   = (float*)(base + 80);
    float2* twN      = (float2*)(base + 256);       // 4224 B
    float*  wnorm    = (float*)(base + 4480);       // 2400 B
    float*  psf_all  = (float*)(base + 6880);       // 9248 B
    float*  A0       = (float*)(base + 16128);      // 16896 B
    float*  A1       = (float*)(base + 33024);      // 16896 B
    float*  Greg     = (float*)(base + 49920);      // NP*4   = 1115136
    float2* Wfilt2   = (float2*)(base + 1165056);   // 2*NP*8 = 4460544
    float2* bufA     = (float2*)(base + 5625600);   // 3*NP*8 = 6690816
    float2* bufB     = (float2*)(base + 12316416);  // 3*NP*8 = 6690816 -> end 19007232

    if (ws_size < 19007232) return;   // proven available (R4)

    detect_k<<<1, 64, 0, stream>>>(image, in_sizes[i_img], blurKernel, in_sizes[i_bk],
                                   wcw, in_sizes[i_wcw], wscale, in_sizes[i_ws],
                                   c4a, c4b, flags, alpha_ws, wgt_ws);
    twinit_k<<<(NN+63)/64, 64, 0, stream>>>(twN);
    wnorm_k<<<1, 64, 0, stream>>>(wcw, wscale, flags, wnorm);
    prep_k<<<8, 64, 0, stream>>>(blurKernel, flags, psf_all, A0, A1);
    greg_k<<<(NP+255)/256, 256, 0, stream>>>(wnorm, twN, Greg);

    dim3 tgrid(NN/16, NN/16, 3), tblk(16, 16);
    int nb3 = (3*NP+255)/256;
    int nb1 = (NP+255)/256;

    for (int b0 = 0; b0 < 8; b0 += 2) {
        packet_k<<<nb3, 256, 0, stream>>>(image, flags, psf_all, A0, A1, bufA, b0);
        fft_pass<<<3*NN, 128, 0, stream>>>(bufA, bufB, twN, 0);     // rows fwd
        transpose_k<<<tgrid, tblk, 0, stream>>>(bufB, bufA);
        fft_pass<<<3*NN, 128, 0, stream>>>(bufA, bufB, twN, 0);     // cols fwd -> Z
        wfiltpair_k<<<nb1, 256, 0, stream>>>(psf_all, b0, Greg, twN, alpha_ws, wgt_ws, Wfilt2);
        cmulpair_k<<<nb3, 256, 0, stream>>>(bufB, Wfilt2, bufA);
        fft_pass<<<3*NN, 128, 0, stream>>>(bufA, bufB, twN, 1);     // cols inv
        transpose_k<<<tgrid, tblk, 0, stream>>>(bufB, bufA);
        fft_pass<<<3*NN, 128, 0, stream>>>(bufA, bufB, twN, 1);     // rows inv
        croppair_k<<<(3*IMGP+255)/256, 256, 0, stream>>>(bufB, out, b0);
    }
}

// Round 9
// 847.749 us; speedup vs baseline: 1.6013x; 1.3718x over previous
//
#include <hip/hip_runtime.h>
#include <hip/hip_bf16.h>

#define NN 528
#define NP (NN*NN)
#define IMG 512
#define IMGP (IMG*IMG)
#define PAD 8
#define KH 17
#define KT (KH*KH)
#define NF 24
#define RK 5
#define RKT (RK*RK)
#define ND 4
// per-channel border pixel counts
#define TOPB (17*NN)            // rows 0..16
#define ROWB (2*TOPB)           // + rows 511..527  = 17952
#define SIDEB (494*34)          // rows 17..510, cols 0..16 & 511..527
#define BORD (ROWB + SIDEB)     // 34748
#define BORD3 (3*BORD)          // 104244

static __device__ __forceinline__ float ldx(const void* p, long i, int bf) {
    if (bf) return __bfloat162float(((const __hip_bfloat16*)p)[i]);
    return ((const float*)p)[i];
}

static __device__ __forceinline__ float fetch_pad(const void* img, long ofs, int bf,
                                                  int rr, int cc) {
    int sr = rr - PAD; sr = sr < 0 ? -sr-1 : (sr >= IMG ? 2*IMG-1-sr : sr);
    int sc = cc - PAD; sc = sc < 0 ? -sc-1 : (sc >= IMG ? 2*IMG-1-sc : sc);
    return ldx(img, ofs + sr*IMG + sc, bf);
}

// flags[0..3]: dtype of image/blurKernel/wcw/wscale; routes size-4 tensors by sign.
__global__ void detect_k(const void* pimg, int nimg, const void* pbk, int nbk,
                         const void* pwcw, int nwcw, const void* pws, int nws,
                         const float* c4a, const float* c4b,
                         int* __restrict__ flags,
                         float* __restrict__ alpha_ws, float* __restrict__ wgt_ws) {
    int t = threadIdx.x;
    const void* ps[4] = {pimg, pbk, pwcw, pws};
    int ns[4] = {nimg, nbk, nwcw, nws};
    if (t < 4) {
        const unsigned short* q = (const unsigned short*)ps[t];
        int n = ns[t];
        int K = n < 512 ? n : 512;
        int cnt = 0, pass = 0;
        for (int i = 0; i < K; i += 2) {
            int e = (q[i] >> 7) & 0xFF;
            pass += (e >= 100 && e <= 140);
            cnt++;
        }
        flags[t] = (pass * 10 >= cnt * 8) ? 1 : 0;
    }
    if (t == 7) {
        const float* A = (c4a[0] < 0.f) ? c4a : c4b;
        const float* W = (c4a[0] < 0.f) ? c4b : c4a;
        for (int i = 0; i < ND; ++i) { alpha_ws[i] = A[i]; wgt_ws[i] = W[i]; }
    }
}

__global__ void twinit_k(float2* __restrict__ twN) {
    int i = blockIdx.x * blockDim.x + threadIdx.x;
    if (i < NN) {
        double th = -6.283185307179586476925287 * (double)i / (double)NN;
        twN[i] = make_float2((float)cos(th), (float)sin(th));
    }
}

__global__ void wnorm_k(const void* __restrict__ wcw, const void* __restrict__ wscale,
                        const int* __restrict__ flags, float* __restrict__ wout) {
    int f = threadIdx.x;
    if (f >= NF) return;
    int bfw = flags[2], bfs = flags[3];
    float v[RKT];
    float mean = 0.f;
    for (int i = 0; i < RKT; ++i) { v[i] = ldx(wcw, f*RKT+i, bfw); mean += v[i]; }
    mean *= (1.f/(float)RKT);
    float ss = 0.f;
    for (int i = 0; i < RKT; ++i) { v[i] -= mean; ss += v[i]*v[i]; }
    float sc = ldx(wscale, f, bfs) / sqrtf(ss);
    for (int i = 0; i < RKT; ++i) wout[f*RKT+i] = v[i]*sc;
}

__global__ void prep_k(const void* __restrict__ blurKernel, const int* __restrict__ flags,
                       float* __restrict__ psf_all, float* __restrict__ A0_all,
                       float* __restrict__ A1_all) {
    int b = blockIdx.x, t = threadIdx.x;
    int bf = flags[1];
    __shared__ float psf[KT];
    __shared__ float q0[KH], q1[KH], ac0[KH], ac1[KH];
    for (int i = t; i < KT; i += 64) {
        float v = ldx(blurKernel, b*KT + i, bf);
        psf[i] = v;
        psf_all[b*KT + i] = v;
    }
    __syncthreads();
    if (t < KH) {
        float s0 = 0.f, s1 = 0.f;
        for (int k = 0; k < KH; ++k) { s0 += psf[t*KH + k]; s1 += psf[k*KH + t]; }
        q0[t] = s0; q1[t] = s1;
    }
    __syncthreads();
    if (t < KH) {
        float a0 = 0.f, a1 = 0.f;
        for (int m = 0; m + t < KH; ++m) { a0 += q0[m]*q0[m+t]; a1 += q1[m]*q1[m+t]; }
        ac0[t] = a0; ac1[t] = a1;
    }
    __syncthreads();
    for (int r = t; r < NN; r += 64) {
        int lag = min(r, (NN-1) - r);
        float b0 = (lag <= KH-1) ? ac0[lag]/ac0[0] : 0.f;
        float b1 = (lag <= KH-1) ? ac1[lag]/ac1[0] : 0.f;
        A0_all[b*NN + r] = 1.f - b0;
        A1_all[b*NN + r] = 1.f - b1;
    }
}

// Greg in transposed frequency layout: p = kc*NN + kr (verified R6)
__global__ void greg_k(const float* __restrict__ w, const float2* __restrict__ twN,
                       float* __restrict__ Greg) {
    int p = blockIdx.x * blockDim.x + threadIdx.x;
    if (p >= NP) return;
    int u = p % NN, v = p / NN;
    float2 rp[RK], cp[RK];
    for (int j = 0; j < RK; ++j) {
        int m = (u * (j - RK/2)) % NN; if (m < 0) m += NN;
        rp[j] = twN[m];
    }
    for (int k = 0; k < RK; ++k) {
        int m = (v * (k - RK/2)) % NN; if (m < 0) m += NN;
        cp[k] = twN[m];
    }
    float pr[RKT], pi[RKT];
    for (int j = 0; j < RK; ++j)
        for (int k = 0; k < RK; ++k) {
            pr[j*RK+k] = rp[j].x*cp[k].x - rp[j].y*cp[k].y;
            pi[j*RK+k] = rp[j].x*cp[k].y + rp[j].y*cp[k].x;
        }
    float acc = 0.f;
    for (int f = 0; f < NF; ++f) {
        float gr = 0.f, gi = 0.f;
        for (int i = 0; i < RKT; ++i) {
            float wv = w[f*RKT + i];
            gr += wv * pr[i];
            gi += wv * pi[i];
        }
        acc += gr*gr + gi*gi;
    }
    Greg[p] = acc;
}

// Wiener filters for BOTH batches of a pair (shared twiddle setup).
__global__ __launch_bounds__(256)
void wfiltpair_k(const float* __restrict__ psf_all, int b0,
                 const float* __restrict__ Greg, const float2* __restrict__ twN,
                 const float* __restrict__ alpha4, const float* __restrict__ wgt4,
                 float2* __restrict__ Wfilt2) {
    __shared__ float sps[2*KT];
    for (int i = threadIdx.x; i < 2*KT; i += 256)
        sps[i] = psf_all[b0*KT + i];
    __syncthreads();
    int p = blockIdx.x * blockDim.x + threadIdx.x;
    if (p >= NP) return;
    int u = p % NN, v = p / NN;
    float2 rph[KH], cph[KH];
    int mu = (520 * u) % NN;   // (-8u) mod 528
    int mv = (520 * v) % NN;
    for (int j = 0; j < KH; ++j) {
        rph[j] = twN[mu]; mu += u; if (mu >= NN) mu -= NN;
        cph[j] = twN[mv]; mv += v; if (mv >= NN) mv -= NN;
    }
    float K0r = 0.f, K0i = 0.f, K1r = 0.f, K1i = 0.f;
    for (int j = 0; j < KH; ++j) {
        float sr0 = 0.f, si0 = 0.f, sr1 = 0.f, si1 = 0.f;
        for (int k = 0; k < KH; ++k) {
            float2 cp = cph[k];
            float p0 = sps[j*KH + k];
            float p1 = sps[KT + j*KH + k];
            sr0 += p0 * cp.x; si0 += p0 * cp.y;
            sr1 += p1 * cp.x; si1 += p1 * cp.y;
        }
        float2 rp = rph[j];
        K0r += rp.x*sr0 - rp.y*si0;  K0i += rp.x*si0 + rp.y*sr0;
        K1r += rp.x*sr1 - rp.y*si1;  K1i += rp.x*si1 + rp.y*sr1;
    }
    float g = Greg[p];
    float K20 = K0r*K0r + K0i*K0i;
    float K21 = K1r*K1r + K1i*K1i;
    float s0 = 0.f, s1 = 0.f;
    for (int d = 0; d < ND; ++d) {
        float a = __expf(alpha4[d]);
        float wd = wgt4[d];
        s0 += wd / fmaxf(K20 + a*g, 1e-30f);
        s1 += wd / fmaxf(K21 + a*g, 1e-30f);
    }
    s0 *= (1.f/(float)NP);
    s1 *= (1.f/(float)NP);
    Wfilt2[p]      = make_float2(K0r*s0, -K0i*s0);
    Wfilt2[NP + p] = make_float2(K1r*s1, -K1i*s1);
}

// bulk pad+pack: out = x_pad(b0) + i*x_pad(b0+1), all pixels (border overwritten later)
__global__ void pad2_k(const void* __restrict__ image, const int* __restrict__ flags,
                       float2* __restrict__ outbuf, int b0) {
    int idx = blockIdx.x * blockDim.x + threadIdx.x;
    if (idx >= 3*NP) return;
    int bf = flags[0];
    int ch = idx / NP, p = idx % NP;
    int r = p / NN, c = p % NN;
    long ofs0 = ((long)b0*3 + ch) * IMGP;
    float x0 = fetch_pad(image, ofs0, bf, r, c);
    float x1 = fetch_pad(image, ofs0 + 3L*IMGP, bf, r, c);
    outbuf[(size_t)ch*NP + p] = make_float2(x0, x1);
}

// border edgetaper: compact thread mapping over the 104244 border pixels; no divergence,
// mirror indices hoisted out of the inner loop (no integer mod inside).
__global__ __launch_bounds__(256)
void border_k(const void* __restrict__ image, const int* __restrict__ flags,
              const float* __restrict__ psf_all,
              const float* __restrict__ A0_all, const float* __restrict__ A1_all,
              float2* __restrict__ outbuf, int b0) {
    __shared__ float sps[2*KT];
    for (int i = threadIdx.x; i < 2*KT; i += 256)
        sps[i] = psf_all[b0*KT + i];
    __syncthreads();
    int idx = blockIdx.x * blockDim.x + threadIdx.x;
    if (idx >= BORD3) return;
    int bf = flags[0];
    int ch = idx / BORD, i = idx % BORD;
    int r, c;
    if (i < TOPB) { r = i / NN; c = i - r*NN; }
    else if (i < ROWB) { int j = i - TOPB; r = 511 + j / NN; c = j - (r-511)*NN; }
    else {
        int j = i - ROWB;
        r = 17 + j / 34;
        int cc = j - (r-17)*34;
        c = (cc < 17) ? cc : 494 + cc;
    }
    long ofs0 = ((long)b0*3 + ch) * IMGP;
    long ofs1 = ofs0 + 3L*IMGP;

    // hoisted mirrored row/col offsets: rr = (r - (j-PAD)) mod NN -> mirror(rr-PAD)
    int rowof[KH], colof[KH];
    #pragma unroll
    for (int j = 0; j < KH; ++j) {
        int rr = r + PAD - j;
        if (rr < 0) rr += NN; else if (rr >= NN) rr -= NN;
        int sr = rr - PAD;
        sr = sr < 0 ? -sr-1 : (sr >= IMG ? 2*IMG-1-sr : sr);
        rowof[j] = sr * IMG;
        int cc2 = c + PAD - j;
        if (cc2 < 0) cc2 += NN; else if (cc2 >= NN) cc2 -= NN;
        int sc = cc2 - PAD;
        sc = sc < 0 ? -sc-1 : (sc >= IMG ? 2*IMG-1-sc : sc);
        colof[j] = sc;
    }
    float bl0 = 0.f, bl1 = 0.f;
    for (int j = 0; j < KH; ++j) {
        long rb0 = ofs0 + rowof[j];
        long rb1 = ofs1 + rowof[j];
        const float* sp0 = sps + j*KH;
        const float* sp1 = sps + KT + j*KH;
        #pragma unroll
        for (int k = 0; k < KH; ++k) {
            int co = colof[k];
            bl0 += sp0[k] * ldx(image, rb0 + co, bf);
            bl1 += sp1[k] * ldx(image, rb1 + co, bf);
        }
    }
    float x0 = fetch_pad(image, ofs0, bf, r, c);
    float x1 = fetch_pad(image, ofs1, bf, r, c);
    float al0 = A0_all[b0*NN + r] * A1_all[b0*NN + c];
    float al1 = A0_all[(b0+1)*NN + r] * A1_all[(b0+1)*NN + c];
    float res0 = al0*x0 + (1.f - al0)*bl0;
    float res1 = al1*x1 + (1.f - al1)*bl1;
    outbuf[(size_t)ch*NP + (size_t)r*NN + c] = make_float2(res0, res1);
}

// 1D FFT (528 = 16*33), one block per row (HW-verified vs naive DFT, R4)
__global__ __launch_bounds__(128)
void fft_pass(const float2* __restrict__ in, float2* __restrict__ out,
              const float2* __restrict__ twN, int inv) {
    __shared__ float2 X[NN];
    __shared__ float2 A[NN];
    __shared__ float2 TW[NN];
    int t = threadIdx.x;
    const float2* src = in + (size_t)blockIdx.x * NN;
    float2* dst = out + (size_t)blockIdx.x * NN;
    for (int i = t; i < NN; i += 128) { X[i] = src[i]; TW[i] = twN[i]; }
    __syncthreads();
    float s = inv ? -1.f : 1.f;
    for (int o = t; o < NN; o += 128) {
        int n1 = o & 15, k2 = o >> 4;
        float ar = 0.f, ai = 0.f;
        int m = 0;
        for (int n2 = 0; n2 < 33; ++n2) {
            float2 xv = X[n1 + 16*n2];
            float2 w = TW[m * 16];
            float wr = w.x, wi = w.y * s;
            ar += xv.x*wr - xv.y*wi;
            ai += xv.x*wi + xv.y*wr;
            m += k2; if (m >= 33) m -= 33;
        }
        float2 tw = TW[n1 * k2];
        float twr = tw.x, twi = tw.y * s;
        A[n1*33 + k2] = make_float2(ar*twr - ai*twi, ar*twi + ai*twr);
    }
    __syncthreads();
    for (int o = t; o < NN; o += 128) {
        int k1 = o / 33, k2 = o - 33*k1;
        float ar = 0.f, ai = 0.f;
        int m = 0;
        for (int n1 = 0; n1 < 16; ++n1) {
            float2 bv = A[n1*33 + k2];
            float2 w = TW[m * 33];
            float wr = w.x, wi = w.y * s;
            ar += bv.x*wr - bv.y*wi;
            ai += bv.x*wi + bv.y*wr;
            m = (m + k1) & 15;
        }
        dst[o] = make_float2(ar, ai);
    }
}

__global__ void transpose_k(const float2* __restrict__ in, float2* __restrict__ out) {
    __shared__ float2 tile[16][17];
    int ch = blockIdx.z;
    int c0 = blockIdx.x * 16, r0 = blockIdx.y * 16;
    const float2* src = in + (size_t)ch * NP;
    float2* dst = out + (size_t)ch * NP;
    int x = c0 + threadIdx.x, y = r0 + threadIdx.y;
    tile[threadIdx.y][threadIdx.x] = src[(size_t)y*NN + x];
    __syncthreads();
    int xo = r0 + threadIdx.x, yo = c0 + threadIdx.y;
    dst[(size_t)yo*NN + xo] = tile[threadIdx.x][threadIdx.y];
}

// Hermitian unpack -> per-batch filter -> repack.
__global__ void cmulpair_k(const float2* __restrict__ in, const float2* __restrict__ Wfilt2,
                           float2* __restrict__ out) {
    int i = blockIdx.x * blockDim.x + threadIdx.x;
    if (i >= 3*NP) return;
    int ch = i / NP, p = i % NP;
    int u = p % NN, v = p / NN;
    int um = (NN - u) % NN, vm = (NN - v) % NN;
    int pm = vm * NN + um;
    float2 Z  = in[(size_t)ch*NP + p];
    float2 Zm = in[(size_t)ch*NP + pm];
    float X0r = 0.5f*(Z.x + Zm.x), X0i = 0.5f*(Z.y - Zm.y);
    float X1r = 0.5f*(Z.y + Zm.y), X1i = 0.5f*(Zm.x - Z.x);
    float2 W0 = Wfilt2[p], W1 = Wfilt2[NP + p];
    float Y0r = X0r*W0.x - X0i*W0.y, Y0i = X0r*W0.y + X0i*W0.x;
    float Y1r = X1r*W1.x - X1i*W1.y, Y1i = X1r*W1.y + X1i*W1.x;
    out[(size_t)ch*NP + p] = make_float2(Y0r - Y1i, Y0i + Y1r);
}

// crop: Re -> batch b0, Im -> batch b0+1
__global__ void croppair_k(const float2* __restrict__ buf, float* __restrict__ out, int b0) {
    int idx = blockIdx.x * blockDim.x + threadIdx.x;
    if (idx >= 3*IMGP) return;
    int ch = idx / IMGP, p = idx % IMGP;
    int r = p / IMG, c = p % IMG;
    float2 v = buf[(size_t)ch*NP + (size_t)(r+PAD)*NN + (c+PAD)];
    out[((size_t)b0*3 + ch) * IMGP + p] = v.x;
    out[((size_t)(b0+1)*3 + ch) * IMGP + p] = v.y;
}

extern "C" void kernel_launch(void* const* d_in, const int* in_sizes, int n_in,
                              void* d_out, int out_size, void* d_ws, size_t ws_size,
                              hipStream_t stream) {
    int i_img = -1, i_bk = -1, i_wcw = -1, i_ws = -1, i_4a = -1, i_4b = -1;
    for (int i = 0; i < n_in; ++i) {
        int s = in_sizes[i];
        if (s == 8*3*IMG*IMG)   i_img = i;
        else if (s == 8*KT)     i_bk = i;
        else if (s == NF*RKT)   i_wcw = i;
        else if (s == NF)       i_ws = i;
        else if (s == ND) { if (i_4a < 0) i_4a = i; else i_4b = i; }
    }
    if (i_img < 0) i_img = 0;
    if (i_bk  < 0) i_bk  = 1;
    if (i_wcw < 0) i_wcw = 3;
    if (i_ws  < 0) i_ws  = 4;
    if (i_4a  < 0) i_4a  = 5;
    if (i_4b  < 0) i_4b  = i_4a;
    const void* image      = d_in[i_img];
    const void* blurKernel = d_in[i_bk];
    const void* wcw        = d_in[i_wcw];
    const void* wscale     = d_in[i_ws];
    const float* c4a       = (const float*)d_in[i_4a];
    const float* c4b       = (const float*)d_in[i_4b];
    float* out = (float*)d_out;

    char* base = (char*)d_ws;
    int*    flags    = (int*)(base);
    float*  alpha_ws = (float*)(base + 64);
    float*  wgt_ws   = (float*)(base + 80);
    float2* twN      = (float2*)(base + 256);
    float*  wnorm    = (float*)(base + 4480);
    float*  psf_all  = (float*)(base + 6880);
    float*  A0       = (float*)(base + 16128);
    float*  A1       = (float*)(base + 33024);
    float*  Greg     = (float*)(base + 49920);      // NP*4
    float2* Wfilt2   = (float2*)(base + 1165056);   // 2*NP*8
    float2* bufA     = (float2*)(base + 5625600);   // 3*NP*8
    float2* bufB     = (float2*)(base + 12316416);  // 3*NP*8 -> end 19007232

    if (ws_size < 19007232) return;

    detect_k<<<1, 64, 0, stream>>>(image, in_sizes[i_img], blurKernel, in_sizes[i_bk],
                                   wcw, in_sizes[i_wcw], wscale, in_sizes[i_ws],
                                   c4a, c4b, flags, alpha_ws, wgt_ws);
    twinit_k<<<(NN+63)/64, 64, 0, stream>>>(twN);
    wnorm_k<<<1, 64, 0, stream>>>(wcw, wscale, flags, wnorm);
    prep_k<<<8, 64, 0, stream>>>(blurKernel, flags, psf_all, A0, A1);
    greg_k<<<(NP+255)/256, 256, 0, stream>>>(wnorm, twN, Greg);

    dim3 tgrid(NN/16, NN/16, 3), tblk(16, 16);
    int nb3 = (3*NP+255)/256;
    int nb1 = (NP+255)/256;

    for (int b0 = 0; b0 < 8; b0 += 2) {
        pad2_k<<<nb3, 256, 0, stream>>>(image, flags, bufA, b0);
        border_k<<<(BORD3+255)/256, 256, 0, stream>>>(image, flags, psf_all, A0, A1, bufA, b0);
        fft_pass<<<3*NN, 128, 0, stream>>>(bufA, bufB, twN, 0);     // rows fwd
        transpose_k<<<tgrid, tblk, 0, stream>>>(bufB, bufA);
        fft_pass<<<3*NN, 128, 0, stream>>>(bufA, bufB, twN, 0);     // cols fwd -> Z
        wfiltpair_k<<<nb1, 256, 0, stream>>>(psf_all, b0, Greg, twN, alpha_ws, wgt_ws, Wfilt2);
        cmulpair_k<<<nb3, 256, 0, stream>>>(bufB, Wfilt2, bufA);
        fft_pass<<<3*NN, 128, 0, stream>>>(bufA, bufB, twN, 1);     // cols inv
        transpose_k<<<tgrid, tblk, 0, stream>>>(bufB, bufA);
        fft_pass<<<3*NN, 128, 0, stream>>>(bufA, bufB, twN, 1);     // rows inv
        croppair_k<<<(3*IMGP+255)/256, 256, 0, stream>>>(bufB, out, b0);
    }
}

// Round 10
// 622.058 us; speedup vs baseline: 2.1823x; 1.3628x over previous
//
#include <hip/hip_runtime.h>
#include <hip/hip_bf16.h>

#define NN 528
#define NP (NN*NN)
#define IMG 512
#define IMGP (IMG*IMG)
#define PAD 8
#define KH 17
#define KT (KH*KH)
#define NF 24
#define RK 5
#define RKT (RK*RK)
#define ND 4
// per-channel border pixel counts
#define TOPB (17*NN)
#define ROWB (2*TOPB)
#define SIDEB (494*34)
#define BORD (ROWB + SIDEB)     // 34748

static __device__ __forceinline__ float ldx(const void* p, long i, int bf) {
    if (bf) return __bfloat162float(((const __hip_bfloat16*)p)[i]);
    return ((const float*)p)[i];
}

static __device__ __forceinline__ float fetch_pad(const void* img, long ofs, int bf,
                                                  int rr, int cc) {
    int sr = rr - PAD; sr = sr < 0 ? -sr-1 : (sr >= IMG ? 2*IMG-1-sr : sr);
    int sc = cc - PAD; sc = sc < 0 ? -sc-1 : (sc >= IMG ? 2*IMG-1-sc : sc);
    return ldx(img, ofs + sr*IMG + sc, bf);
}

__global__ void detect_k(const void* pimg, int nimg, const void* pbk, int nbk,
                         const void* pwcw, int nwcw, const void* pws, int nws,
                         const float* c4a, const float* c4b,
                         int* __restrict__ flags,
                         float* __restrict__ alpha_ws, float* __restrict__ wgt_ws) {
    int t = threadIdx.x;
    const void* ps[4] = {pimg, pbk, pwcw, pws};
    int ns[4] = {nimg, nbk, nwcw, nws};
    if (t < 4) {
        const unsigned short* q = (const unsigned short*)ps[t];
        int n = ns[t];
        int K = n < 512 ? n : 512;
        int cnt = 0, pass = 0;
        for (int i = 0; i < K; i += 2) {
            int e = (q[i] >> 7) & 0xFF;
            pass += (e >= 100 && e <= 140);
            cnt++;
        }
        flags[t] = (pass * 10 >= cnt * 8) ? 1 : 0;
    }
    if (t == 7) {
        const float* A = (c4a[0] < 0.f) ? c4a : c4b;
        const float* W = (c4a[0] < 0.f) ? c4b : c4a;
        for (int i = 0; i < ND; ++i) { alpha_ws[i] = A[i]; wgt_ws[i] = W[i]; }
    }
}

__global__ void twinit_k(float2* __restrict__ twN) {
    int i = blockIdx.x * blockDim.x + threadIdx.x;
    if (i < NN) {
        double th = -6.283185307179586476925287 * (double)i / (double)NN;
        twN[i] = make_float2((float)cos(th), (float)sin(th));
    }
}

__global__ void wnorm_k(const void* __restrict__ wcw, const void* __restrict__ wscale,
                        const int* __restrict__ flags, float* __restrict__ wout) {
    int f = threadIdx.x;
    if (f >= NF) return;
    int bfw = flags[2], bfs = flags[3];
    float v[RKT];
    float mean = 0.f;
    for (int i = 0; i < RKT; ++i) { v[i] = ldx(wcw, f*RKT+i, bfw); mean += v[i]; }
    mean *= (1.f/(float)RKT);
    float ss = 0.f;
    for (int i = 0; i < RKT; ++i) { v[i] -= mean; ss += v[i]*v[i]; }
    float sc = ldx(wscale, f, bfs) / sqrtf(ss);
    for (int i = 0; i < RKT; ++i) wout[f*RKT+i] = v[i]*sc;
}

__global__ void prep_k(const void* __restrict__ blurKernel, const int* __restrict__ flags,
                       float* __restrict__ psf_all, float* __restrict__ A0_all,
                       float* __restrict__ A1_all) {
    int b = blockIdx.x, t = threadIdx.x;
    int bf = flags[1];
    __shared__ float psf[KT];
    __shared__ float q0[KH], q1[KH], ac0[KH], ac1[KH];
    for (int i = t; i < KT; i += 64) {
        float v = ldx(blurKernel, b*KT + i, bf);
        psf[i] = v;
        psf_all[b*KT + i] = v;
    }
    __syncthreads();
    if (t < KH) {
        float s0 = 0.f, s1 = 0.f;
        for (int k = 0; k < KH; ++k) { s0 += psf[t*KH + k]; s1 += psf[k*KH + t]; }
        q0[t] = s0; q1[t] = s1;
    }
    __syncthreads();
    if (t < KH) {
        float a0 = 0.f, a1 = 0.f;
        for (int m = 0; m + t < KH; ++m) { a0 += q0[m]*q0[m+t]; a1 += q1[m]*q1[m+t]; }
        ac0[t] = a0; ac1[t] = a1;
    }
    __syncthreads();
    for (int r = t; r < NN; r += 64) {
        int lag = min(r, (NN-1) - r);
        float b0 = (lag <= KH-1) ? ac0[lag]/ac0[0] : 0.f;
        float b1 = (lag <= KH-1) ? ac1[lag]/ac1[0] : 0.f;
        A0_all[b*NN + r] = 1.f - b0;
        A1_all[b*NN + r] = 1.f - b1;
    }
}

// Greg in transposed frequency layout: p = kc*NN + kr (verified R6)
__global__ void greg_k(const float* __restrict__ w, const float2* __restrict__ twN,
                       float* __restrict__ Greg) {
    int p = blockIdx.x * blockDim.x + threadIdx.x;
    if (p >= NP) return;
    int u = p % NN, v = p / NN;
    float2 rp[RK], cp[RK];
    for (int j = 0; j < RK; ++j) {
        int m = (u * (j - RK/2)) % NN; if (m < 0) m += NN;
        rp[j] = twN[m];
    }
    for (int k = 0; k < RK; ++k) {
        int m = (v * (k - RK/2)) % NN; if (m < 0) m += NN;
        cp[k] = twN[m];
    }
    float pr[RKT], pi[RKT];
    for (int j = 0; j < RK; ++j)
        for (int k = 0; k < RK; ++k) {
            pr[j*RK+k] = rp[j].x*cp[k].x - rp[j].y*cp[k].y;
            pi[j*RK+k] = rp[j].x*cp[k].y + rp[j].y*cp[k].x;
        }
    float acc = 0.f;
    for (int f = 0; f < NF; ++f) {
        float gr = 0.f, gi = 0.f;
        for (int i = 0; i < RKT; ++i) {
            float wv = w[f*RKT + i];
            gr += wv * pr[i];
            gi += wv * pi[i];
        }
        acc += gr*gr + gi*gi;
    }
    Greg[p] = acc;
}

// bulk pad+pack for 6 planes (2 pairs): plane q = pair*3+ch holds x_pad(b0p)+i*x_pad(b0p+1)
__global__ void pad6_k(const void* __restrict__ image, const int* __restrict__ flags,
                       float2* __restrict__ buf, int B0) {
    int idx = blockIdx.x * blockDim.x + threadIdx.x;
    if (idx >= 6*NP) return;
    int bf = flags[0];
    int q = idx / NP, p = idx % NP;
    int pair = q / 3, ch = q - 3*pair;
    int b0p = B0 + 2*pair;
    int r = p / NN, c = p % NN;
    long ofs0 = ((long)b0p*3 + ch) * IMGP;
    float x0 = fetch_pad(image, ofs0, bf, r, c);
    float x1 = fetch_pad(image, ofs0 + 3L*IMGP, bf, r, c);
    buf[(size_t)q*NP + p] = make_float2(x0, x1);
}

// border edgetaper for 6 planes; compact mapping, hoisted mirror indices
__global__ __launch_bounds__(256)
void border6_k(const void* __restrict__ image, const int* __restrict__ flags,
               const float* __restrict__ psf_all,
               const float* __restrict__ A0_all, const float* __restrict__ A1_all,
               float2* __restrict__ buf, int B0) {
    __shared__ float sps[4*KT];
    for (int i = threadIdx.x; i < 4*KT; i += 256)
        sps[i] = psf_all[B0*KT + i];
    __syncthreads();
    int idx = blockIdx.x * blockDim.x + threadIdx.x;
    if (idx >= 6*BORD) return;
    int bf = flags[0];
    int q = idx / BORD, i = idx % BORD;
    int pair = q / 3, ch = q - 3*pair;
    int b0p = B0 + 2*pair;
    int r, c;
    if (i < TOPB) { r = i / NN; c = i - r*NN; }
    else if (i < ROWB) { int j = i - TOPB; r = 511 + j / NN; c = j - (r-511)*NN; }
    else {
        int j = i - ROWB;
        r = 17 + j / 34;
        int cc = j - (r-17)*34;
        c = (cc < 17) ? cc : 494 + cc;
    }
    long ofs0 = ((long)b0p*3 + ch) * IMGP;
    long ofs1 = ofs0 + 3L*IMGP;
    int rowof[KH], colof[KH];
    #pragma unroll
    for (int j = 0; j < KH; ++j) {
        int rr = r + PAD - j;
        if (rr < 0) rr += NN; else if (rr >= NN) rr -= NN;
        int sr = rr - PAD;
        sr = sr < 0 ? -sr-1 : (sr >= IMG ? 2*IMG-1-sr : sr);
        rowof[j] = sr * IMG;
        int cc2 = c + PAD - j;
        if (cc2 < 0) cc2 += NN; else if (cc2 >= NN) cc2 -= NN;
        int sc = cc2 - PAD;
        sc = sc < 0 ? -sc-1 : (sc >= IMG ? 2*IMG-1-sc : sc);
        colof[j] = sc;
    }
    const float* sp0 = sps + pair*2*KT;
    const float* sp1 = sp0 + KT;
    float bl0 = 0.f, bl1 = 0.f;
    for (int j = 0; j < KH; ++j) {
        long rb0 = ofs0 + rowof[j];
        long rb1 = ofs1 + rowof[j];
        #pragma unroll
        for (int k = 0; k < KH; ++k) {
            int co = colof[k];
            bl0 += sp0[j*KH + k] * ldx(image, rb0 + co, bf);
            bl1 += sp1[j*KH + k] * ldx(image, rb1 + co, bf);
        }
    }
    float x0 = fetch_pad(image, ofs0, bf, r, c);
    float x1 = fetch_pad(image, ofs1, bf, r, c);
    float al0 = A0_all[b0p*NN + r] * A1_all[b0p*NN + c];
    float al1 = A0_all[(b0p+1)*NN + r] * A1_all[(b0p+1)*NN + c];
    buf[(size_t)q*NP + (size_t)r*NN + c] =
        make_float2(al0*x0 + (1.f-al0)*bl0, al1*x1 + (1.f-al1)*bl1);
}

// 1D FFT (528=16*33), one block per row; safe with in==out (full row staged in LDS)
__global__ __launch_bounds__(128)
void fft_pass(const float2* __restrict__ in, float2* __restrict__ out,
              const float2* __restrict__ twN, int inv) {
    __shared__ float2 X[NN];
    __shared__ float2 A[NN];
    __shared__ float2 TW[NN];
    int t = threadIdx.x;
    const float2* src = in + (size_t)blockIdx.x * NN;
    float2* dst = out + (size_t)blockIdx.x * NN;
    for (int i = t; i < NN; i += 128) { X[i] = src[i]; TW[i] = twN[i]; }
    __syncthreads();
    float s = inv ? -1.f : 1.f;
    for (int o = t; o < NN; o += 128) {
        int n1 = o & 15, k2 = o >> 4;
        float ar = 0.f, ai = 0.f;
        int m = 0;
        for (int n2 = 0; n2 < 33; ++n2) {
            float2 xv = X[n1 + 16*n2];
            float2 w = TW[m * 16];
            float wr = w.x, wi = w.y * s;
            ar += xv.x*wr - xv.y*wi;
            ai += xv.x*wi + xv.y*wr;
            m += k2; if (m >= 33) m -= 33;
        }
        float2 tw = TW[n1 * k2];
        float twr = tw.x, twi = tw.y * s;
        A[n1*33 + k2] = make_float2(ar*twr - ai*twi, ar*twi + ai*twr);
    }
    __syncthreads();
    for (int o = t; o < NN; o += 128) {
        int k1 = o / 33, k2 = o - 33*k1;
        float ar = 0.f, ai = 0.f;
        int m = 0;
        for (int n1 = 0; n1 < 16; ++n1) {
            float2 bv = A[n1*33 + k2];
            float2 w = TW[m * 33];
            float wr = w.x, wi = w.y * s;
            ar += bv.x*wr - bv.y*wi;
            ai += bv.x*wi + bv.y*wr;
            m = (m + k1) & 15;
        }
        dst[o] = make_float2(ar, ai);
    }
}

// in-place square transpose: tile-pair swap, 561 upper-tri tiles per plane
__global__ void transpose_ip_k(float2* __restrict__ buf) {
    int tnum = blockIdx.x;
    int ti = 0, rem = tnum;
    while (rem >= 33 - ti) { rem -= 33 - ti; ti++; }
    int tj = ti + rem;
    float2* pl = buf + (size_t)blockIdx.z * NP;
    __shared__ float2 ta[16][17], tb[16][17];
    int tx = threadIdx.x, ty = threadIdx.y;
    int ra = ti*16 + ty, ca = tj*16 + tx;
    int rb = tj*16 + ty, cb = ti*16 + tx;
    ta[ty][tx] = pl[(size_t)ra*NN + ca];
    tb[ty][tx] = pl[(size_t)rb*NN + cb];
    __syncthreads();
    pl[(size_t)ra*NN + ca] = tb[tx][ty];
    pl[(size_t)rb*NN + cb] = ta[tx][ty];
}

// fused Wiener filter + Hermitian unpack/apply/repack, in-place, one thread per (p,pm) pair
__global__ __launch_bounds__(256)
void cmulw_k(float2* __restrict__ buf, const float* __restrict__ psf_all,
             const float* __restrict__ Greg, const float2* __restrict__ twN,
             const float* __restrict__ alpha4, const float* __restrict__ wgt4, int B0) {
    int pair = blockIdx.y;
    int b0p = B0 + 2*pair;
    __shared__ float sps[2*KT];
    for (int i = threadIdx.x; i < 2*KT; i += 256)
        sps[i] = psf_all[b0p*KT + i];
    __syncthreads();
    int p = blockIdx.x * blockDim.x + threadIdx.x;
    if (p >= NP) return;
    int u = p % NN, v = p / NN;
    int um = (NN - u) % NN, vm = (NN - v) % NN;
    int pm = vm * NN + um;
    if (pm < p) return;                      // each Hermitian pair handled once
    // K for both batches (incremental twiddle phase; verified scheme R8/R9)
    float2 rph[KH], cph[KH];
    int mu = (520 * u) % NN;
    int mv = (520 * v) % NN;
    for (int j = 0; j < KH; ++j) {
        rph[j] = twN[mu]; mu += u; if (mu >= NN) mu -= NN;
        cph[j] = twN[mv]; mv += v; if (mv >= NN) mv -= NN;
    }
    float K0r = 0.f, K0i = 0.f, K1r = 0.f, K1i = 0.f;
    for (int j = 0; j < KH; ++j) {
        float sr0 = 0.f, si0 = 0.f, sr1 = 0.f, si1 = 0.f;
        for (int k = 0; k < KH; ++k) {
            float2 cp = cph[k];
            float p0 = sps[j*KH + k];
            float p1 = sps[KT + j*KH + k];
            sr0 += p0 * cp.x; si0 += p0 * cp.y;
            sr1 += p1 * cp.x; si1 += p1 * cp.y;
        }
        float2 rp = rph[j];
        K0r += rp.x*sr0 - rp.y*si0;  K0i += rp.x*si0 + rp.y*sr0;
        K1r += rp.x*sr1 - rp.y*si1;  K1i += rp.x*si1 + rp.y*sr1;
    }
    float g = Greg[p];
    float K20 = K0r*K0r + K0i*K0i;
    float K21 = K1r*K1r + K1i*K1i;
    float s0 = 0.f, s1 = 0.f;
    for (int d = 0; d < ND; ++d) {
        float a = __expf(alpha4[d]);
        float wd = wgt4[d];
        s0 += wd / fmaxf(K20 + a*g, 1e-30f);
        s1 += wd / fmaxf(K21 + a*g, 1e-30f);
    }
    s0 *= (1.f/(float)NP);
    s1 *= (1.f/(float)NP);
    float W0r = K0r*s0, W0i = -K0i*s0;
    float W1r = K1r*s1, W1i = -K1i*s1;
    float2* pl = buf + (size_t)pair*3*NP;
    for (int ch = 0; ch < 3; ++ch) {
        float2 Z  = pl[(size_t)ch*NP + p];
        float2 Zm = pl[(size_t)ch*NP + pm];
        float X0r = 0.5f*(Z.x + Zm.x), X0i = 0.5f*(Z.y - Zm.y);
        float X1r = 0.5f*(Z.y + Zm.y), X1i = 0.5f*(Zm.x - Z.x);
        float Y0r = X0r*W0r - X0i*W0i, Y0i = X0r*W0i + X0i*W0r;
        float Y1r = X1r*W1r - X1i*W1i, Y1i = X1r*W1i + X1i*W1r;
        pl[(size_t)ch*NP + p]  = make_float2(Y0r - Y1i, Y0i + Y1r);
        pl[(size_t)ch*NP + pm] = make_float2(Y0r + Y1i, Y1r - Y0i);   // conj relation
    }
}

// final inverse row-FFT fused with crop: computes only cols 8..519, writes fp32 out
__global__ __launch_bounds__(128)
void fft_crop_k(const float2* __restrict__ in, float* __restrict__ out,
                const float2* __restrict__ twN, int B0) {
    __shared__ float2 X[NN];
    __shared__ float2 A[NN];
    __shared__ float2 TW[NN];
    int t = threadIdx.x;
    int q = blockIdx.x >> 9;            // plane 0..5
    int rp = (blockIdx.x & 511) + PAD;  // padded row 8..519
    int pair = q / 3, ch = q - 3*pair;
    int b0p = B0 + 2*pair;
    const float2* src = in + (size_t)q*NP + (size_t)rp*NN;
    for (int i = t; i < NN; i += 128) { X[i] = src[i]; TW[i] = twN[i]; }
    __syncthreads();
    const float s = -1.f;   // inverse
    for (int o = t; o < NN; o += 128) {
        int n1 = o & 15, k2 = o >> 4;
        float ar = 0.f, ai = 0.f;
        int m = 0;
        for (int n2 = 0; n2 < 33; ++n2) {
            float2 xv = X[n1 + 16*n2];
            float2 w = TW[m * 16];
            float wr = w.x, wi = w.y * s;
            ar += xv.x*wr - xv.y*wi;
            ai += xv.x*wi + xv.y*wr;
            m += k2; if (m >= 33) m -= 33;
        }
        float2 tw = TW[n1 * k2];
        float twr = tw.x, twi = tw.y * s;
        A[n1*33 + k2] = make_float2(ar*twr - ai*twi, ar*twi + ai*twr);
    }
    __syncthreads();
    float* o0 = out + ((size_t)b0p*3 + ch) * IMGP + (size_t)(rp - PAD) * IMG;
    float* o1 = o0 + 3L*IMGP;
    for (int o = PAD + t; o < IMG + PAD; o += 128) {   // 512 outputs, 4/thread
        int k1 = o / 33, k2 = o - 33*k1;
        float ar = 0.f, ai = 0.f;
        int m = 0;
        for (int n1 = 0; n1 < 16; ++n1) {
            float2 bv = A[n1*33 + k2];
            float2 w = TW[m * 33];
            float wr = w.x, wi = w.y * s;
            ar += bv.x*wr - bv.y*wi;
            ai += bv.x*wi + bv.y*wr;
            m = (m + k1) & 15;
        }
        o0[o - PAD] = ar;
        o1[o - PAD] = ai;
    }
}

extern "C" void kernel_launch(void* const* d_in, const int* in_sizes, int n_in,
                              void* d_out, int out_size, void* d_ws, size_t ws_size,
                              hipStream_t stream) {
    int i_img = -1, i_bk = -1, i_wcw = -1, i_ws = -1, i_4a = -1, i_4b = -1;
    for (int i = 0; i < n_in; ++i) {
        int s = in_sizes[i];
        if (s == 8*3*IMG*IMG)   i_img = i;
        else if (s == 8*KT)     i_bk = i;
        else if (s == NF*RKT)   i_wcw = i;
        else if (s == NF)       i_ws = i;
        else if (s == ND) { if (i_4a < 0) i_4a = i; else i_4b = i; }
    }
    if (i_img < 0) i_img = 0;
    if (i_bk  < 0) i_bk  = 1;
    if (i_wcw < 0) i_wcw = 3;
    if (i_ws  < 0) i_ws  = 4;
    if (i_4a  < 0) i_4a  = 5;
    if (i_4b  < 0) i_4b  = i_4a;
    const void* image      = d_in[i_img];
    const void* blurKernel = d_in[i_bk];
    const void* wcw        = d_in[i_wcw];
    const void* wscale     = d_in[i_ws];
    const float* c4a       = (const float*)d_in[i_4a];
    const float* c4b       = (const float*)d_in[i_4b];
    float* out = (float*)d_out;

    char* base = (char*)d_ws;
    int*    flags    = (int*)(base);
    float*  alpha_ws = (float*)(base + 64);
    float*  wgt_ws   = (float*)(base + 80);
    float2* twN      = (float2*)(base + 256);
    float*  wnorm    = (float*)(base + 4480);
    float*  psf_all  = (float*)(base + 6880);
    float*  A0       = (float*)(base + 16128);
    float*  A1       = (float*)(base + 33024);
    float*  Greg     = (float*)(base + 49920);      // NP*4 = 1115136
    float2* buf      = (float2*)(base + 1165056);   // 6*NP*8 = 13381632 -> end 14546688

    if (ws_size < 14546688) return;

    detect_k<<<1, 64, 0, stream>>>(image, in_sizes[i_img], blurKernel, in_sizes[i_bk],
                                   wcw, in_sizes[i_wcw], wscale, in_sizes[i_ws],
                                   c4a, c4b, flags, alpha_ws, wgt_ws);
    twinit_k<<<(NN+63)/64, 64, 0, stream>>>(twN);
    wnorm_k<<<1, 64, 0, stream>>>(wcw, wscale, flags, wnorm);
    prep_k<<<8, 64, 0, stream>>>(blurKernel, flags, psf_all, A0, A1);
    greg_k<<<(NP+255)/256, 256, 0, stream>>>(wnorm, twN, Greg);

    dim3 tblk(16, 16);
    dim3 tgrid6(561, 1, 6);
    dim3 cgrid((NP+255)/256, 2);

    for (int B0 = 0; B0 < 8; B0 += 4) {
        pad6_k<<<(6*NP+255)/256, 256, 0, stream>>>(image, flags, buf, B0);
        border6_k<<<(6*BORD+255)/256, 256, 0, stream>>>(image, flags, psf_all, A0, A1, buf, B0);
        fft_pass<<<6*NN, 128, 0, stream>>>(buf, buf, twN, 0);        // rows fwd (in-place)
        transpose_ip_k<<<tgrid6, tblk, 0, stream>>>(buf);
        fft_pass<<<6*NN, 128, 0, stream>>>(buf, buf, twN, 0);        // cols fwd
        cmulw_k<<<cgrid, 256, 0, stream>>>(buf, psf_all, Greg, twN, alpha_ws, wgt_ws, B0);
        fft_pass<<<6*NN, 128, 0, stream>>>(buf, buf, twN, 1);        // cols inv
        transpose_ip_k<<<tgrid6, tblk, 0, stream>>>(buf);
        fft_crop_k<<<6*IMG, 128, 0, stream>>>(buf, out, twN, B0);    // rows inv + crop
    }
}

// Round 11
// 557.662 us; speedup vs baseline: 2.4343x; 1.1155x over previous
//
#include <hip/hip_runtime.h>
#include <hip/hip_bf16.h>

#define NN 528
#define NP (NN*NN)
#define IMG 512
#define IMGP (IMG*IMG)
#define PAD 8
#define KH 17
#define KT (KH*KH)
#define NF 24
#define RK 5
#define RKT (RK*RK)
#define ND 4
// per-channel border pixel counts
#define TOPB (17*NN)
#define ROWB (2*TOPB)
#define SIDEB (494*34)
#define BORD (ROWB + SIDEB)     // 34748

static __device__ __forceinline__ float ldx(const void* p, long i, int bf) {
    if (bf) return __bfloat162float(((const __hip_bfloat16*)p)[i]);
    return ((const float*)p)[i];
}

static __device__ __forceinline__ float fetch_pad(const void* img, long ofs, int bf,
                                                  int rr, int cc) {
    int sr = rr - PAD; sr = sr < 0 ? -sr-1 : (sr >= IMG ? 2*IMG-1-sr : sr);
    int sc = cc - PAD; sc = sc < 0 ? -sc-1 : (sc >= IMG ? 2*IMG-1-sc : sc);
    return ldx(img, ofs + sr*IMG + sc, bf);
}

__global__ void detect_k(const void* pimg, int nimg, const void* pbk, int nbk,
                         const void* pwcw, int nwcw, const void* pws, int nws,
                         const float* c4a, const float* c4b,
                         int* __restrict__ flags,
                         float* __restrict__ alpha_ws, float* __restrict__ wgt_ws) {
    int t = threadIdx.x;
    const void* ps[4] = {pimg, pbk, pwcw, pws};
    int ns[4] = {nimg, nbk, nwcw, nws};
    if (t < 4) {
        const unsigned short* q = (const unsigned short*)ps[t];
        int n = ns[t];
        int K = n < 512 ? n : 512;
        int cnt = 0, pass = 0;
        for (int i = 0; i < K; i += 2) {
            int e = (q[i] >> 7) & 0xFF;
            pass += (e >= 100 && e <= 140);
            cnt++;
        }
        flags[t] = (pass * 10 >= cnt * 8) ? 1 : 0;
    }
    if (t == 7) {
        const float* A = (c4a[0] < 0.f) ? c4a : c4b;
        const float* W = (c4a[0] < 0.f) ? c4b : c4a;
        for (int i = 0; i < ND; ++i) { alpha_ws[i] = A[i]; wgt_ws[i] = W[i]; }
    }
}

__global__ void twinit_k(float2* __restrict__ twN) {
    int i = blockIdx.x * blockDim.x + threadIdx.x;
    if (i < NN) {
        double th = -6.283185307179586476925287 * (double)i / (double)NN;
        twN[i] = make_float2((float)cos(th), (float)sin(th));
    }
}

__global__ void wnorm_k(const void* __restrict__ wcw, const void* __restrict__ wscale,
                        const int* __restrict__ flags, float* __restrict__ wout) {
    int f = threadIdx.x;
    if (f >= NF) return;
    int bfw = flags[2], bfs = flags[3];
    float v[RKT];
    float mean = 0.f;
    for (int i = 0; i < RKT; ++i) { v[i] = ldx(wcw, f*RKT+i, bfw); mean += v[i]; }
    mean *= (1.f/(float)RKT);
    float ss = 0.f;
    for (int i = 0; i < RKT; ++i) { v[i] -= mean; ss += v[i]*v[i]; }
    float sc = ldx(wscale, f, bfs) / sqrtf(ss);
    for (int i = 0; i < RKT; ++i) wout[f*RKT+i] = v[i]*sc;
}

__global__ void prep_k(const void* __restrict__ blurKernel, const int* __restrict__ flags,
                       float* __restrict__ psf_all, float* __restrict__ A0_all,
                       float* __restrict__ A1_all) {
    int b = blockIdx.x, t = threadIdx.x;
    int bf = flags[1];
    __shared__ float psf[KT];
    __shared__ float q0[KH], q1[KH], ac0[KH], ac1[KH];
    for (int i = t; i < KT; i += 64) {
        float v = ldx(blurKernel, b*KT + i, bf);
        psf[i] = v;
        psf_all[b*KT + i] = v;
    }
    __syncthreads();
    if (t < KH) {
        float s0 = 0.f, s1 = 0.f;
        for (int k = 0; k < KH; ++k) { s0 += psf[t*KH + k]; s1 += psf[k*KH + t]; }
        q0[t] = s0; q1[t] = s1;
    }
    __syncthreads();
    if (t < KH) {
        float a0 = 0.f, a1 = 0.f;
        for (int m = 0; m + t < KH; ++m) { a0 += q0[m]*q0[m+t]; a1 += q1[m]*q1[m+t]; }
        ac0[t] = a0; ac1[t] = a1;
    }
    __syncthreads();
    for (int r = t; r < NN; r += 64) {
        int lag = min(r, (NN-1) - r);
        float b0 = (lag <= KH-1) ? ac0[lag]/ac0[0] : 0.f;
        float b1 = (lag <= KH-1) ? ac1[lag]/ac1[0] : 0.f;
        A0_all[b*NN + r] = 1.f - b0;
        A1_all[b*NN + r] = 1.f - b1;
    }
}

// Greg in transposed frequency layout: p = kc*NN + kr (verified R6)
__global__ void greg_k(const float* __restrict__ w, const float2* __restrict__ twN,
                       float* __restrict__ Greg) {
    int p = blockIdx.x * blockDim.x + threadIdx.x;
    if (p >= NP) return;
    int u = p % NN, v = p / NN;
    float2 rp[RK], cp[RK];
    for (int j = 0; j < RK; ++j) {
        int m = (u * (j - RK/2)) % NN; if (m < 0) m += NN;
        rp[j] = twN[m];
    }
    for (int k = 0; k < RK; ++k) {
        int m = (v * (k - RK/2)) % NN; if (m < 0) m += NN;
        cp[k] = twN[m];
    }
    float pr[RKT], pi[RKT];
    for (int j = 0; j < RK; ++j)
        for (int k = 0; k < RK; ++k) {
            pr[j*RK+k] = rp[j].x*cp[k].x - rp[j].y*cp[k].y;
            pi[j*RK+k] = rp[j].x*cp[k].y + rp[j].y*cp[k].x;
        }
    float acc = 0.f;
    for (int f = 0; f < NF; ++f) {
        float gr = 0.f, gi = 0.f;
        for (int i = 0; i < RKT; ++i) {
            float wv = w[f*RKT + i];
            gr += wv * pr[i];
            gi += wv * pi[i];
        }
        acc += gr*gr + gi*gi;
    }
    Greg[p] = acc;
}

// ALL-batch border edgetaper: one thread per (batch-plane, border-pixel), one batch each.
// grid: (ceil(BORD/256), 24). Massive parallelism hides L1/L2 load latency.
__global__ __launch_bounds__(256)
void border_all_k(const void* __restrict__ image, const int* __restrict__ flags,
                  const float* __restrict__ psf_all,
                  const float* __restrict__ A0_all, const float* __restrict__ A1_all,
                  float* __restrict__ borderV) {
    int bp = blockIdx.y;            // 0..23
    int b = bp / 3, ch = bp - 3*b;
    __shared__ float sps[KT];
    for (int i = threadIdx.x; i < KT; i += 256) sps[i] = psf_all[b*KT + i];
    __syncthreads();
    int i = blockIdx.x * blockDim.x + threadIdx.x;
    if (i >= BORD) return;
    int bf = flags[0];
    int r, c;
    if (i < TOPB) { r = i / NN; c = i - r*NN; }
    else if (i < ROWB) { int j = i - TOPB; r = 511 + j / NN; c = j - (r-511)*NN; }
    else {
        int j = i - ROWB;
        r = 17 + j / 34;
        int cc = j - (r-17)*34;
        c = (cc < 17) ? cc : 494 + cc;
    }
    long ofs = ((long)b*3 + ch) * IMGP;
    int rowof[KH], colof[KH];
    #pragma unroll
    for (int j = 0; j < KH; ++j) {
        int rr = r + PAD - j;
        if (rr < 0) rr += NN; else if (rr >= NN) rr -= NN;
        int sr = rr - PAD;
        sr = sr < 0 ? -sr-1 : (sr >= IMG ? 2*IMG-1-sr : sr);
        rowof[j] = sr * IMG;
        int cc2 = c + PAD - j;
        if (cc2 < 0) cc2 += NN; else if (cc2 >= NN) cc2 -= NN;
        int sc = cc2 - PAD;
        sc = sc < 0 ? -sc-1 : (sc >= IMG ? 2*IMG-1-sc : sc);
        colof[j] = sc;
    }
    float bl = 0.f;
    for (int j = 0; j < KH; ++j) {
        long rb = ofs + rowof[j];
        #pragma unroll
        for (int k = 0; k < KH; ++k)
            bl += sps[j*KH + k] * ldx(image, rb + colof[k], bf);
    }
    float x = fetch_pad(image, ofs, bf, r, c);
    float al = A0_all[b*NN + r] * A1_all[b*NN + c];
    borderV[(size_t)bp*BORD + i] = al*x + (1.f - al)*bl;
}

// bulk pad+pack for 6 planes; border pixels read precomputed borderV
__global__ void pad6_k(const void* __restrict__ image, const int* __restrict__ flags,
                       const float* __restrict__ borderV,
                       float2* __restrict__ buf, int B0) {
    int idx = blockIdx.x * blockDim.x + threadIdx.x;
    if (idx >= 6*NP) return;
    int bf = flags[0];
    int q = idx / NP, p = idx % NP;
    int pair = q / 3, ch = q - 3*pair;
    int b0p = B0 + 2*pair;
    int r = p / NN, c = p % NN;
    float x0, x1;
    bool isb = (r < 17) | (r >= 511) | (c < 17) | (c >= 511);
    if (isb) {
        int i2;
        if (r < 17) i2 = r*NN + c;
        else if (r >= 511) i2 = TOPB + (r-511)*NN + c;
        else { int cc = (c < 17) ? c : c - 494; i2 = ROWB + (r-17)*34 + cc; }
        x0 = borderV[(size_t)(b0p*3 + ch)*BORD + i2];
        x1 = borderV[(size_t)((b0p+1)*3 + ch)*BORD + i2];
    } else {
        // interior: no mirroring possible (sr,sc in 9..502)
        long ofs0 = ((long)b0p*3 + ch) * IMGP + (long)(r - PAD)*IMG + (c - PAD);
        x0 = ldx(image, ofs0, bf);
        x1 = ldx(image, ofs0 + 3L*IMGP, bf);
    }
    buf[(size_t)q*NP + p] = make_float2(x0, x1);
}

// 1D FFT (528=16*33), one block per row; safe with in==out (full row staged in LDS)
__global__ __launch_bounds__(128)
void fft_pass(const float2* __restrict__ in, float2* __restrict__ out,
              const float2* __restrict__ twN, int inv) {
    __shared__ float2 X[NN];
    __shared__ float2 A[NN];
    __shared__ float2 TW[NN];
    int t = threadIdx.x;
    const float2* src = in + (size_t)blockIdx.x * NN;
    float2* dst = out + (size_t)blockIdx.x * NN;
    for (int i = t; i < NN; i += 128) { X[i] = src[i]; TW[i] = twN[i]; }
    __syncthreads();
    float s = inv ? -1.f : 1.f;
    for (int o = t; o < NN; o += 128) {
        int n1 = o & 15, k2 = o >> 4;
        float ar = 0.f, ai = 0.f;
        int m = 0;
        for (int n2 = 0; n2 < 33; ++n2) {
            float2 xv = X[n1 + 16*n2];
            float2 w = TW[m * 16];
            float wr = w.x, wi = w.y * s;
            ar += xv.x*wr - xv.y*wi;
            ai += xv.x*wi + xv.y*wr;
            m += k2; if (m >= 33) m -= 33;
        }
        float2 tw = TW[n1 * k2];
        float twr = tw.x, twi = tw.y * s;
        A[n1*33 + k2] = make_float2(ar*twr - ai*twi, ar*twi + ai*twr);
    }
    __syncthreads();
    for (int o = t; o < NN; o += 128) {
        int k1 = o / 33, k2 = o - 33*k1;
        float ar = 0.f, ai = 0.f;
        int m = 0;
        for (int n1 = 0; n1 < 16; ++n1) {
            float2 bv = A[n1*33 + k2];
            float2 w = TW[m * 33];
            float wr = w.x, wi = w.y * s;
            ar += bv.x*wr - bv.y*wi;
            ai += bv.x*wi + bv.y*wr;
            m = (m + k1) & 15;
        }
        dst[o] = make_float2(ar, ai);
    }
}

// in-place square transpose: tile-pair swap, 561 upper-tri tiles per plane
__global__ void transpose_ip_k(float2* __restrict__ buf) {
    int tnum = blockIdx.x;
    int ti = 0, rem = tnum;
    while (rem >= 33 - ti) { rem -= 33 - ti; ti++; }
    int tj = ti + rem;
    float2* pl = buf + (size_t)blockIdx.z * NP;
    __shared__ float2 ta[16][17], tb[16][17];
    int tx = threadIdx.x, ty = threadIdx.y;
    int ra = ti*16 + ty, ca = tj*16 + tx;
    int rb = tj*16 + ty, cb = ti*16 + tx;
    ta[ty][tx] = pl[(size_t)ra*NN + ca];
    tb[ty][tx] = pl[(size_t)rb*NN + cb];
    __syncthreads();
    pl[(size_t)ra*NN + ca] = tb[tx][ty];
    pl[(size_t)rb*NN + cb] = ta[tx][ty];
}

// column-sum factor S(b, v, j) = sum_k psf[b][j][k] * tw[v*(k-8)]  (u-independent part of K)
__global__ void kv_k(const float* __restrict__ psf_all, const float2* __restrict__ twN,
                     float2* __restrict__ Sv) {
    int idx = blockIdx.x * blockDim.x + threadIdx.x;
    if (idx >= 8*NN*KH) return;
    int j = idx % KH;
    int rest = idx / KH;
    int v = rest % NN, b = rest / NN;
    int m = (520 * v) % NN;   // (-8v) mod 528
    float sr = 0.f, si = 0.f;
    const float* ps = psf_all + b*KT + j*KH;
    for (int k = 0; k < KH; ++k) {
        float2 cp = twN[m];
        m += v; if (m >= NN) m -= NN;
        sr += ps[k] * cp.x;
        si += ps[k] * cp.y;
    }
    Sv[idx] = make_float2(sr, si);
}

// fused Wiener filter + Hermitian unpack/apply/repack, in-place; K via Sv factorization
__global__ __launch_bounds__(256)
void cmulw2_k(float2* __restrict__ buf, const float2* __restrict__ Sv,
              const float* __restrict__ Greg, const float2* __restrict__ twN,
              const float* __restrict__ alpha4, const float* __restrict__ wgt4, int B0) {
    int pair = blockIdx.y;
    int b0p = B0 + 2*pair;
    __shared__ float2 tw[NN];
    for (int i = threadIdx.x; i < NN; i += 256) tw[i] = twN[i];
    __syncthreads();
    int p = blockIdx.x * blockDim.x + threadIdx.x;
    if (p >= NP) return;
    int u = p % NN, v = p / NN;
    int um = (NN - u) % NN, vm = (NN - v) % NN;
    int pm = vm * NN + um;
    if (pm < p) return;
    const float2* S0 = Sv + ((size_t)(b0p    )*NN + v)*KH;
    const float2* S1 = Sv + ((size_t)(b0p + 1)*NN + v)*KH;
    int mu = (520 * u) % NN;
    float K0r = 0.f, K0i = 0.f, K1r = 0.f, K1i = 0.f;
    for (int j = 0; j < KH; ++j) {
        float2 rp = tw[mu]; mu += u; if (mu >= NN) mu -= NN;
        float2 s0 = S0[j], s1 = S1[j];
        K0r += rp.x*s0.x - rp.y*s0.y;  K0i += rp.x*s0.y + rp.y*s0.x;
        K1r += rp.x*s1.x - rp.y*s1.y;  K1i += rp.x*s1.y + rp.y*s1.x;
    }
    float g = Greg[p];
    float K20 = K0r*K0r + K0i*K0i;
    float K21 = K1r*K1r + K1i*K1i;
    float s0 = 0.f, s1 = 0.f;
    for (int d = 0; d < ND; ++d) {
        float a = __expf(alpha4[d]);
        float wd = wgt4[d];
        s0 += wd / fmaxf(K20 + a*g, 1e-30f);
        s1 += wd / fmaxf(K21 + a*g, 1e-30f);
    }
    s0 *= (1.f/(float)NP);
    s1 *= (1.f/(float)NP);
    float W0r = K0r*s0, W0i = -K0i*s0;
    float W1r = K1r*s1, W1i = -K1i*s1;
    float2* pl = buf + (size_t)pair*3*NP;
    for (int ch = 0; ch < 3; ++ch) {
        float2 Z  = pl[(size_t)ch*NP + p];
        float2 Zm = pl[(size_t)ch*NP + pm];
        float X0r = 0.5f*(Z.x + Zm.x), X0i = 0.5f*(Z.y - Zm.y);
        float X1r = 0.5f*(Z.y + Zm.y), X1i = 0.5f*(Zm.x - Z.x);
        float Y0r = X0r*W0r - X0i*W0i, Y0i = X0r*W0i + X0i*W0r;
        float Y1r = X1r*W1r - X1i*W1i, Y1i = X1r*W1i + X1i*W1r;
        pl[(size_t)ch*NP + p]  = make_float2(Y0r - Y1i, Y0i + Y1r);
        pl[(size_t)ch*NP + pm] = make_float2(Y0r + Y1i, Y1r - Y0i);
    }
}

// final inverse row-FFT fused with crop: computes only cols 8..519, writes fp32 out
__global__ __launch_bounds__(128)
void fft_crop_k(const float2* __restrict__ in, float* __restrict__ out,
                const float2* __restrict__ twN, int B0) {
    __shared__ float2 X[NN];
    __shared__ float2 A[NN];
    __shared__ float2 TW[NN];
    int t = threadIdx.x;
    int q = blockIdx.x >> 9;
    int rp = (blockIdx.x & 511) + PAD;
    int pair = q / 3, ch = q - 3*pair;
    int b0p = B0 + 2*pair;
    const float2* src = in + (size_t)q*NP + (size_t)rp*NN;
    for (int i = t; i < NN; i += 128) { X[i] = src[i]; TW[i] = twN[i]; }
    __syncthreads();
    const float s = -1.f;
    for (int o = t; o < NN; o += 128) {
        int n1 = o & 15, k2 = o >> 4;
        float ar = 0.f, ai = 0.f;
        int m = 0;
        for (int n2 = 0; n2 < 33; ++n2) {
            float2 xv = X[n1 + 16*n2];
            float2 w = TW[m * 16];
            float wr = w.x, wi = w.y * s;
            ar += xv.x*wr - xv.y*wi;
            ai += xv.x*wi + xv.y*wr;
            m += k2; if (m >= 33) m -= 33;
        }
        float2 tw = TW[n1 * k2];
        float twr = tw.x, twi = tw.y * s;
        A[n1*33 + k2] = make_float2(ar*twr - ai*twi, ar*twi + ai*twr);
    }
    __syncthreads();
    float* o0 = out + ((size_t)b0p*3 + ch) * IMGP + (size_t)(rp - PAD) * IMG;
    float* o1 = o0 + 3L*IMGP;
    for (int o = PAD + t; o < IMG + PAD; o += 128) {
        int k1 = o / 33, k2 = o - 33*k1;
        float ar = 0.f, ai = 0.f;
        int m = 0;
        for (int n1 = 0; n1 < 16; ++n1) {
            float2 bv = A[n1*33 + k2];
            float2 w = TW[m * 33];
            float wr = w.x, wi = w.y * s;
            ar += bv.x*wr - bv.y*wi;
            ai += bv.x*wi + bv.y*wr;
            m = (m + k1) & 15;
        }
        o0[o - PAD] = ar;
        o1[o - PAD] = ai;
    }
}

extern "C" void kernel_launch(void* const* d_in, const int* in_sizes, int n_in,
                              void* d_out, int out_size, void* d_ws, size_t ws_size,
                              hipStream_t stream) {
    int i_img = -1, i_bk = -1, i_wcw = -1, i_ws = -1, i_4a = -1, i_4b = -1;
    for (int i = 0; i < n_in; ++i) {
        int s = in_sizes[i];
        if (s == 8*3*IMG*IMG)   i_img = i;
        else if (s == 8*KT)     i_bk = i;
        else if (s == NF*RKT)   i_wcw = i;
        else if (s == NF)       i_ws = i;
        else if (s == ND) { if (i_4a < 0) i_4a = i; else i_4b = i; }
    }
    if (i_img < 0) i_img = 0;
    if (i_bk  < 0) i_bk  = 1;
    if (i_wcw < 0) i_wcw = 3;
    if (i_ws  < 0) i_ws  = 4;
    if (i_4a  < 0) i_4a  = 5;
    if (i_4b  < 0) i_4b  = i_4a;
    const void* image      = d_in[i_img];
    const void* blurKernel = d_in[i_bk];
    const void* wcw        = d_in[i_wcw];
    const void* wscale     = d_in[i_ws];
    const float* c4a       = (const float*)d_in[i_4a];
    const float* c4b       = (const float*)d_in[i_4b];
    float* out = (float*)d_out;

    char* base = (char*)d_ws;
    int*    flags    = (int*)(base);
    float*  alpha_ws = (float*)(base + 64);
    float*  wgt_ws   = (float*)(base + 80);
    float2* twN      = (float2*)(base + 256);
    float*  wnorm    = (float*)(base + 4480);
    float*  psf_all  = (float*)(base + 6880);
    float*  A0       = (float*)(base + 16128);
    float*  A1       = (float*)(base + 33024);
    float*  Greg     = (float*)(base + 49920);      // NP*4 = 1115136
    float2* buf      = (float2*)(base + 1165056);   // 6*NP*8 = 13381632
    float*  borderV  = (float*)(base + 14546688);   // 24*BORD*4 = 3335808
    float2* Sv       = (float2*)(base + 17882496);  // 8*NN*KH*8 = 574464 -> end 18456960

    if (ws_size < 18456960) return;

    detect_k<<<1, 64, 0, stream>>>(image, in_sizes[i_img], blurKernel, in_sizes[i_bk],
                                   wcw, in_sizes[i_wcw], wscale, in_sizes[i_ws],
                                   c4a, c4b, flags, alpha_ws, wgt_ws);
    twinit_k<<<(NN+63)/64, 64, 0, stream>>>(twN);
    wnorm_k<<<1, 64, 0, stream>>>(wcw, wscale, flags, wnorm);
    prep_k<<<8, 64, 0, stream>>>(blurKernel, flags, psf_all, A0, A1);
    greg_k<<<(NP+255)/256, 256, 0, stream>>>(wnorm, twN, Greg);
    kv_k<<<(8*NN*KH+255)/256, 256, 0, stream>>>(psf_all, twN, Sv);

    dim3 bgrid((BORD+255)/256, 24);
    border_all_k<<<bgrid, 256, 0, stream>>>(image, flags, psf_all, A0, A1, borderV);

    dim3 tblk(16, 16);
    dim3 tgrid6(561, 1, 6);
    dim3 cgrid((NP+255)/256, 2);

    for (int B0 = 0; B0 < 8; B0 += 4) {
        pad6_k<<<(6*NP+255)/256, 256, 0, stream>>>(image, flags, borderV, buf, B0);
        fft_pass<<<6*NN, 128, 0, stream>>>(buf, buf, twN, 0);        // rows fwd (in-place)
        transpose_ip_k<<<tgrid6, tblk, 0, stream>>>(buf);
        fft_pass<<<6*NN, 128, 0, stream>>>(buf, buf, twN, 0);        // cols fwd
        cmulw2_k<<<cgrid, 256, 0, stream>>>(buf, Sv, Greg, twN, alpha_ws, wgt_ws, B0);
        fft_pass<<<6*NN, 128, 0, stream>>>(buf, buf, twN, 1);        // cols inv
        transpose_ip_k<<<tgrid6, tblk, 0, stream>>>(buf);
        fft_crop_k<<<6*IMG, 128, 0, stream>>>(buf, out, twN, B0);    // rows inv + crop
    }
}